// Round 9
// baseline (2126.170 us; speedup 1.0000x reference)
//
#include <hip/hip_runtime.h>
#include <math.h>

// ---------------- problem constants ----------------
#define Lsz   1024
#define Tsz   32
#define Bsz   64
#define DIN   300
#define REG   36
#define Rsz   128
#define R3sz  384
#define H3sz  3072
#define GENROWS 49152   // R3sz * Rsz
#define NC    2048      // caption columns c = t*64 + b
#define KPAD  304       // DIN padded to /16

__device__ __forceinline__ float sigf(float x) { return 1.f / (1.f + __expf(-x)); }

// =====================================================================
// Generic tiled SGEMM (64x64 tile, 4x4 reg tile), row-major C.
// z-dim selects a second problem. Used only for q/k projections now.
// =====================================================================
__global__ __launch_bounds__(256) void gemm_bias(
    const float* __restrict__ A, int lda,
    const float* __restrict__ W1, const float* __restrict__ W2, int ldw, int woff,
    const float* __restrict__ bias1, const float* __restrict__ bias2,
    float* __restrict__ C1, float* __restrict__ C2,
    int M, int N, int K)
{
    const float* W = blockIdx.z ? W2 : W1;
    const float* bias = blockIdx.z ? bias2 : bias1;
    float* C = blockIdx.z ? C2 : C1;
    __shared__ float As[16][68];
    __shared__ float Ws[16][68];
    int tid = threadIdx.x;
    int tx = tid & 15, ty = tid >> 4;
    int m0 = blockIdx.y * 64, n0 = blockIdx.x * 64;
    float acc[4][4];
#pragma unroll
    for (int i = 0; i < 4; i++)
#pragma unroll
        for (int j = 0; j < 4; j++) acc[i][j] = 0.f;

    for (int k0 = 0; k0 < K; k0 += 16) {
#pragma unroll
        for (int l = 0; l < 4; l++) {
            int e = l * 256 + tid;
            int kk = e & 15, mm = e >> 4;
            int m = m0 + mm, k = k0 + kk;
            As[kk][mm] = (m < M && k < K) ? A[(size_t)m * lda + k] : 0.f;
        }
#pragma unroll
        for (int l = 0; l < 4; l++) {
            int e = l * 256 + tid;
            int kk = e & 15, nn = e >> 4;
            int n = n0 + nn, k = k0 + kk;
            Ws[kk][nn] = (n < N && k < K) ? W[(size_t)n * ldw + woff + k] : 0.f;
        }
        __syncthreads();
#pragma unroll
        for (int kk = 0; kk < 16; kk++) {
            float4 a4 = *(const float4*)&As[kk][ty * 4];
            float4 w4 = *(const float4*)&Ws[kk][tx * 4];
            float av[4] = {a4.x, a4.y, a4.z, a4.w};
            float wv[4] = {w4.x, w4.y, w4.z, w4.w};
#pragma unroll
            for (int i = 0; i < 4; i++)
#pragma unroll
                for (int j = 0; j < 4; j++) acc[i][j] = fmaf(av[i], wv[j], acc[i][j]);
        }
        __syncthreads();
    }
#pragma unroll
    for (int i = 0; i < 4; i++) {
        int m = m0 + ty * 4 + i;
        if (m >= M) continue;
#pragma unroll
        for (int j = 0; j < 4; j++) {
            int n = n0 + tx * 4 + j;
            if (n >= N) continue;
            C[(size_t)m * N + n] = acc[i][j] + (bias ? bias[n] : 0.f);
        }
    }
}

// =====================================================================
// Generic transpose: out[c*R + r] = in[r*lda + woff + c], c < Cin,
// zero-pad c in [Cin, Cpad). grid (ceil(Cpad/64), ceil(R/64)).
// =====================================================================
__global__ __launch_bounds__(256) void transp_kernel(
    const float* __restrict__ in, float* __restrict__ out,
    int R, int Cin, int Cpad, int lda, int woff)
{
    __shared__ float s[64][65];
    int c0 = blockIdx.x * 64, r0 = blockIdx.y * 64;
    int tid = threadIdx.x;
#pragma unroll
    for (int l = 0; l < 16; l++) {
        int e = l * 256 + tid;
        int rr = e >> 6, cc = e & 63;
        int r = r0 + rr, c = c0 + cc;
        s[rr][cc] = (r < R && c < Cin) ? in[(size_t)r * lda + woff + c] : 0.f;
    }
    __syncthreads();
#pragma unroll
    for (int l = 0; l < 16; l++) {
        int e = l * 256 + tid;
        int cc = e >> 6, rr = e & 63;
        int c = c0 + cc, r = r0 + rr;
        if (c < Cpad && r < R) out[(size_t)c * R + r] = s[rr][cc];
    }
}

// =====================================================================
// Gen-weight transpose: [i][384][128] -> [i][128][384]. grid (2,6,128).
// =====================================================================
__global__ __launch_bounds__(256) void trans_gen(
    const float* __restrict__ WihAll, const float* __restrict__ WhhAll,
    float* __restrict__ WihAllT, float* __restrict__ WhhAllT)
{
    __shared__ float s[64][65];
    int z = blockIdx.z;
    int i = z >> 1, mat = z & 1;
    const float* in = (mat ? WhhAll : WihAll) + (size_t)i * GENROWS;
    float* out      = (mat ? WhhAllT : WihAllT) + (size_t)i * GENROWS;
    int c0 = blockIdx.x * 64, r0 = blockIdx.y * 64;
    int tid = threadIdx.x;
#pragma unroll
    for (int l = 0; l < 16; l++) {
        int e = l * 256 + tid;
        int rr = e >> 6, cc = e & 63;
        s[rr][cc] = in[(size_t)(r0 + rr) * Rsz + c0 + cc];
    }
    __syncthreads();
#pragma unroll
    for (int l = 0; l < 16; l++) {
        int e = l * 256 + tid;
        int cc = e >> 6, rr = e & 63;
        out[(size_t)(c0 + cc) * R3sz + r0 + rr] = s[rr][cc];
    }
}

// =====================================================================
// cap_embed [b][t][d] -> capTr [k][t*64+b], k zero-padded to 304.
// =====================================================================
__global__ __launch_bounds__(256) void captr_kernel(
    const float* __restrict__ cap_embed, float* __restrict__ capTr)
{
    __shared__ float s[64][65];
    int t = blockIdx.x, kc = blockIdx.y;
    int tid = threadIdx.x;
#pragma unroll
    for (int l = 0; l < 16; l++) {
        int e = l * 256 + tid;
        int b = e >> 6, kk = e & 63;
        int k = kc * 64 + kk;
        s[b][kk] = (k < DIN) ? cap_embed[((size_t)b * Tsz + t) * DIN + k] : 0.f;
    }
    __syncthreads();
#pragma unroll
    for (int l = 0; l < 16; l++) {
        int e = l * 256 + tid;
        int kk = e >> 6, b = e & 63;
        int k = kc * 64 + kk;
        if (k < KPAD)
            capTr[(size_t)k * NC + t * 64 + b] = s[b][kk];
    }
}

// =====================================================================
// All-transposed GEMM for gi: C[n][c] = sum_k WT[k][n]*X[k][c] + bias[n].
// WT [KPAD][Ntot], X [KPAD][NC]. Tile 128x128, 8x8 reg tile.
// =====================================================================
__global__ __launch_bounds__(256) void gemm_tt(
    const float* __restrict__ WT1, const float* __restrict__ WT2,
    const float* __restrict__ X,
    const float* __restrict__ b1, const float* __restrict__ b2,
    float* __restrict__ C1, float* __restrict__ C2, int Ntot)
{
    const float* WT = blockIdx.z ? WT2 : WT1;
    const float* bias = blockIdx.z ? b2 : b1;
    float* C = blockIdx.z ? C2 : C1;
    __shared__ float Ws[16][132];
    __shared__ float Xs[16][132];
    int tid = threadIdx.x, tx = tid & 15, ty = tid >> 4;
    int c0 = blockIdx.x * 128, n0 = blockIdx.y * 128;
    float acc[8][8];
#pragma unroll
    for (int i = 0; i < 8; i++)
#pragma unroll
        for (int j = 0; j < 8; j++) acc[i][j] = 0.f;

    for (int k0 = 0; k0 < KPAD; k0 += 16) {
#pragma unroll
        for (int l = 0; l < 2; l++) {
            int e = l * 256 + tid;
            int l16 = e & 15, seg = e >> 4;
            int kk = seg & 15, half = seg >> 4;
            int col = half * 64 + l16 * 4;
            *(float4*)&Ws[kk][col] = *(const float4*)&WT[(size_t)(k0 + kk) * Ntot + n0 + col];
            *(float4*)&Xs[kk][col] = *(const float4*)&X[(size_t)(k0 + kk) * NC + c0 + col];
        }
        __syncthreads();
#pragma unroll
        for (int kk = 0; kk < 16; kk++) {
            float a[8], x[8];
            *(float4*)&a[0] = *(const float4*)&Ws[kk][ty * 8];
            *(float4*)&a[4] = *(const float4*)&Ws[kk][ty * 8 + 4];
            *(float4*)&x[0] = *(const float4*)&Xs[kk][tx * 8];
            *(float4*)&x[4] = *(const float4*)&Xs[kk][tx * 8 + 4];
#pragma unroll
            for (int i = 0; i < 8; i++)
#pragma unroll
                for (int j = 0; j < 8; j++) acc[i][j] = fmaf(a[i], x[j], acc[i][j]);
        }
        __syncthreads();
    }
#pragma unroll
    for (int i = 0; i < 8; i++) {
        int n = n0 + ty * 8 + i;
        float bv = bias[n];
        *(float4*)&C[(size_t)n * NC + c0 + tx * 8] =
            make_float4(acc[i][0] + bv, acc[i][1] + bv, acc[i][2] + bv, acc[i][3] + bv);
        *(float4*)&C[(size_t)n * NC + c0 + tx * 8 + 4] =
            make_float4(acc[i][4] + bv, acc[i][5] + bv, acc[i][6] + bv, acc[i][7] + bv);
    }
}

// =====================================================================
// Parametrized TT GEMM with K-split: z selects k-range [z*klen,(z+1)*klen)
// and writes a separate partial buffer C + z*Ntot*ncols. No bias.
// WT [Ktot][Ntot], X [Ktot][ncols]. grid (ncols/128, Ntot/128, ksplit).
// =====================================================================
__global__ __launch_bounds__(256) void gemm_ttp(
    const float* __restrict__ WT, const float* __restrict__ X,
    float* __restrict__ C, int Ntot, int ncols, int klen)
{
    int z = blockIdx.z;
    int kbase = z * klen;
    float* Cp = C + (size_t)z * Ntot * ncols;
    __shared__ float Ws[16][132];
    __shared__ float Xs[16][132];
    int tid = threadIdx.x, tx = tid & 15, ty = tid >> 4;
    int c0 = blockIdx.x * 128, n0 = blockIdx.y * 128;
    float acc[8][8];
#pragma unroll
    for (int i = 0; i < 8; i++)
#pragma unroll
        for (int j = 0; j < 8; j++) acc[i][j] = 0.f;

    for (int k0 = 0; k0 < klen; k0 += 16) {
#pragma unroll
        for (int l = 0; l < 2; l++) {
            int e = l * 256 + tid;
            int l16 = e & 15, seg = e >> 4;
            int kk = seg & 15, half = seg >> 4;
            int col = half * 64 + l16 * 4;
            *(float4*)&Ws[kk][col] =
                *(const float4*)&WT[(size_t)(kbase + k0 + kk) * Ntot + n0 + col];
            *(float4*)&Xs[kk][col] =
                *(const float4*)&X[(size_t)(kbase + k0 + kk) * ncols + c0 + col];
        }
        __syncthreads();
#pragma unroll
        for (int kk = 0; kk < 16; kk++) {
            float a[8], x[8];
            *(float4*)&a[0] = *(const float4*)&Ws[kk][ty * 8];
            *(float4*)&a[4] = *(const float4*)&Ws[kk][ty * 8 + 4];
            *(float4*)&x[0] = *(const float4*)&Xs[kk][tx * 8];
            *(float4*)&x[4] = *(const float4*)&Xs[kk][tx * 8 + 4];
#pragma unroll
            for (int i = 0; i < 8; i++)
#pragma unroll
                for (int j = 0; j < 8; j++) acc[i][j] = fmaf(a[i], x[j], acc[i][j]);
        }
        __syncthreads();
    }
#pragma unroll
    for (int i = 0; i < 8; i++) {
        int n = n0 + ty * 8 + i;
        *(float4*)&Cp[(size_t)n * ncols + c0 + tx * 8] =
            make_float4(acc[i][0], acc[i][1], acc[i][2], acc[i][3]);
        *(float4*)&Cp[(size_t)n * ncols + c0 + tx * 8 + 4] =
            make_float4(acc[i][4], acc[i][5], acc[i][6], acc[i][7]);
    }
}

// =====================================================================
// Generated weights: out[i][rk] = dot(genW[rk][:], base[i][:]) + bias[rk].
// =====================================================================
__global__ __launch_bounds__(256) void genw_kernel(
    const float* __restrict__ gen_Wih, const float* __restrict__ gen_bih,
    const float* __restrict__ gen_Whh, const float* __restrict__ gen_bhh,
    const float* __restrict__ gen_Wbih, const float* __restrict__ gen_bbih,
    const float* __restrict__ gen_Wbhh, const float* __restrict__ gen_bbhh,
    const float* __restrict__ base,
    float* __restrict__ WihAll, float* __restrict__ WhhAll,
    float* __restrict__ bihAll, float* __restrict__ bhhAll)
{
    int z = blockIdx.y;
    const float* W; const float* bi; float* out; int nr; int rk;
    if (blockIdx.x < 192) {
        rk = blockIdx.x * 256 + threadIdx.x;
        W = z ? gen_Whh : gen_Wih;  bi = z ? gen_bhh : gen_bih;
        out = z ? WhhAll : WihAll;  nr = GENROWS;
    } else {
        rk = (blockIdx.x - 192) * 256 + threadIdx.x;
        if (rk >= R3sz) return;
        W = z ? gen_Wbhh : gen_Wbih; bi = z ? gen_bbhh : gen_bbih;
        out = z ? bhhAll : bihAll;   nr = R3sz;
    }
    const float* wrow = W + (size_t)rk * Rsz;
    float acc[64];
#pragma unroll
    for (int i = 0; i < 64; i++) acc[i] = 0.f;
    for (int pc = 0; pc < Rsz; pc += 16) {
        float w[16];
        *(float4*)&w[0]  = *(const float4*)&wrow[pc];
        *(float4*)&w[4]  = *(const float4*)&wrow[pc + 4];
        *(float4*)&w[8]  = *(const float4*)&wrow[pc + 8];
        *(float4*)&w[12] = *(const float4*)&wrow[pc + 12];
#pragma unroll
        for (int i = 0; i < 64; i++) {
            const float4* bp = (const float4*)(base + (size_t)i * Rsz + pc);
            float4 b0 = bp[0], b1 = bp[1], b2 = bp[2], b3 = bp[3];
            float s = acc[i];
            s = fmaf(w[0], b0.x, s);  s = fmaf(w[1], b0.y, s);
            s = fmaf(w[2], b0.z, s);  s = fmaf(w[3], b0.w, s);
            s = fmaf(w[4], b1.x, s);  s = fmaf(w[5], b1.y, s);
            s = fmaf(w[6], b1.z, s);  s = fmaf(w[7], b1.w, s);
            s = fmaf(w[8], b2.x, s);  s = fmaf(w[9], b2.y, s);
            s = fmaf(w[10], b2.z, s); s = fmaf(w[11], b2.w, s);
            s = fmaf(w[12], b3.x, s); s = fmaf(w[13], b3.y, s);
            s = fmaf(w[14], b3.z, s); s = fmaf(w[15], b3.w, s);
            acc[i] = s;
        }
    }
    float bv = bi[rk];
#pragma unroll
    for (int i = 0; i < 64; i++)
        out[(size_t)i * nr + rk] = acc[i] + bv;
}

// =====================================================================
// Fused image-side precompute. grid 64.
// =====================================================================
__global__ __launch_bounds__(256) void img_kernel(
    const float* __restrict__ img_embed, const float* __restrict__ W_reduce_img,
    const float* __restrict__ b_reduce_img,
    float* __restrict__ base, float* __restrict__ iv)
{
    int i = blockIdx.x;
    int tid = threadIdx.x;
    __shared__ float row[Lsz];
    __shared__ float ps[4];
    for (int c = tid; c < Lsz; c += 256) {
        float s = 0.f;
        for (int r = 0; r < REG; r++) s += img_embed[((size_t)i * REG + r) * Lsz + c];
        row[c] = s * (1.f / (float)REG);
    }
    __syncthreads();
    float ss = 0.f;
    for (int c = tid; c < Lsz; c += 256) { float x = row[c]; ss = fmaf(x, x, ss); }
#pragma unroll
    for (int off = 32; off; off >>= 1) ss += __shfl_down(ss, off, 64);
    int lane = tid & 63, w = tid >> 6;
    if (lane == 0) ps[w] = ss;
    __syncthreads();
    float inv = 1.f / (sqrtf(ps[0] + ps[1] + ps[2] + ps[3]) + 1e-8f);
    for (int c = tid; c < Lsz; c += 256)
        iv[(size_t)i * Lsz + c] = row[c] * inv;
    for (int o = w * 32; o < w * 32 + 32; o++) {
        float a = 0.f;
        const float* wr = W_reduce_img + (size_t)o * Lsz + lane * 16;
        const float* rr = row + lane * 16;
#pragma unroll
        for (int u = 0; u < 16; u++) a = fmaf(wr[u], rr[u], a);
#pragma unroll
        for (int off = 32; off; off >>= 1) a += __shfl_down(a, off, 64);
        if (lane == 0) base[(size_t)i * Rsz + o] = a + b_reduce_img[o];
    }
}

// =====================================================================
// Recurrence phase A, K-chunk 32 (8 barriers/block instead of 16).
// grid 512 x 256 thr. Same decomposition as R8.
// =====================================================================
__global__ __launch_bounds__(256) void step_gemm2(
    const float* __restrict__ hfT, const float* __restrict__ hbT,
    const float* __restrict__ WhhT_f, const float* __restrict__ WhhT_b,
    const float* __restrict__ capT2,
    const float* __restrict__ WihAllT, const float* __restrict__ WhhAllT,
    const float* __restrict__ hprevT,
    float* __restrict__ pcap, float* __restrict__ pgen, int step)
{
    __shared__ float As[32][196];
    __shared__ float Hs[32][68];
    int tid = threadIdx.x;
    int tx = tid & 15, ty = tid >> 4;
    int bid = blockIdx.x;

    const float* WT; const float* X; float* P;
    int ldn, gstride, jg, kbase;
    size_t xstride;

    if (bid < 256) {
        if (step == 0) return;
        int dir = bid >> 7; int rem = bid & 127;
        jg = rem >> 3; int ks = rem & 7;
        WT = dir ? WhhT_b : WhhT_f;        // [1024][3072]
        kbase = ks * 128;
        const float* hT = dir ? hbT : hfT;
        int t  = dir ? (Tsz - 1 - step) : step;
        int tp = dir ? (t + 1) : (t - 1);
        X = hT + ((size_t)tp * Lsz + ks * 128) * Bsz;
        xstride = Bsz;
        P = pcap + ((((size_t)dir * 8 + ks) * 16 + jg) * 192) * 64;
        ldn = H3sz; gstride = Lsz;
    } else {
        int g = bid - 256;
        int x = g & 7, rest = g >> 3;
        int i = x + 8 * (rest >> 2);
        int sub = rest & 3; int ks = sub >> 1; jg = sub & 1;
        if (ks == 1 && step == 0) return;
        WT = (ks ? WhhAllT : WihAllT) + (size_t)i * GENROWS;   // [128][384]
        kbase = 0;
        if (ks) { X = hprevT + (size_t)i * Rsz * Bsz; xstride = Bsz; }
        else    { X = capT2 + (size_t)step * 64;      xstride = NC;  }
        P = pgen + ((((size_t)i * 2 + ks) * 2 + jg) * 192) * 64;
        ldn = R3sz; gstride = Rsz;
    }

    float acc[12][4];
#pragma unroll
    for (int i = 0; i < 12; i++)
#pragma unroll
        for (int j = 0; j < 4; j++) acc[i][j] = 0.f;

    for (int c = 0; c < 4; c++) {
        int k0 = c * 32;
#pragma unroll
        for (int l = 0; l < 6; l++) {
            int e = l * 256 + tid;
            int l16 = e & 15, seg = e >> 4;        // seg < 96
            int kk = seg & 31, gate = seg >> 5;    // gate in 0..2
            const float* src = WT + (size_t)(kbase + k0 + kk) * ldn
                               + gate * gstride + jg * 64 + l16 * 4;
            *(float4*)&As[kk][gate * 64 + l16 * 4] = *(const float4*)src;
        }
#pragma unroll
        for (int l = 0; l < 2; l++) {
            int e = l * 256 + tid;
            int l16 = e & 15, kk = e >> 4;         // kk < 32
            *(float4*)&Hs[kk][l16 * 4] =
                *(const float4*)&X[(size_t)(k0 + kk) * xstride + l16 * 4];
        }
        __syncthreads();
#pragma unroll
        for (int kk = 0; kk < 32; kk++) {
            float a[12], hb[4];
            *(float4*)&a[0] = *(const float4*)&As[kk][ty * 12];
            *(float4*)&a[4] = *(const float4*)&As[kk][ty * 12 + 4];
            *(float4*)&a[8] = *(const float4*)&As[kk][ty * 12 + 8];
            *(float4*)&hb[0] = *(const float4*)&Hs[kk][tx * 4];
#pragma unroll
            for (int i = 0; i < 12; i++)
#pragma unroll
                for (int j = 0; j < 4; j++) acc[i][j] = fmaf(a[i], hb[j], acc[i][j]);
        }
        __syncthreads();
    }
#pragma unroll
    for (int i = 0; i < 12; i++) {
        int mm = ty * 12 + i;
        *(float4*)&P[(size_t)mm * 64 + tx * 4] =
            make_float4(acc[i][0], acc[i][1], acc[i][2], acc[i][3]);
    }
}

// =====================================================================
// Recurrence phase B: reduce K-slices + gates. grid 640 x 256.
// =====================================================================
__global__ __launch_bounds__(256) void step_gates2(
    const float* __restrict__ pcap, const float* __restrict__ pgen,
    const float* __restrict__ giT2_f, const float* __restrict__ giT2_b,
    float* __restrict__ hfT, float* __restrict__ hbT,
    const float* __restrict__ bhh_f, const float* __restrict__ bhh_b,
    const float* __restrict__ bihAll, const float* __restrict__ bhhAll,
    const float* __restrict__ hprevT, float* __restrict__ hcurT,
    float* __restrict__ hmaxT, int step)
{
    int tid = threadIdx.x;
    int b = tid & 63;
    int bid = blockIdx.x;
    if (bid < 128) {
        int dir = bid >> 6; int rem = bid & 63;
        int jg = rem >> 2, q = rem & 3;
        const float* giT = dir ? giT2_b : giT2_f;
        float* hT        = dir ? hbT   : hfT;
        const float* bhh = dir ? bhh_b : bhh_f;
        int t  = dir ? (Tsz - 1 - step) : step;
        int tp = dir ? (t + 1) : (t - 1);
#pragma unroll
        for (int u = 0; u < 4; u++) {
            int jl = q * 16 + u * 4 + (tid >> 6);
            int j = jg * 64 + jl;
            float gh[3] = {0.f, 0.f, 0.f};
            if (step > 0) {
#pragma unroll
                for (int ks = 0; ks < 8; ks++) {
                    const float* pb = pcap + ((((size_t)dir * 8 + ks) * 16 + jg) * 192) * 64;
#pragma unroll
                    for (int g = 0; g < 3; g++)
                        gh[g] += pb[(size_t)(g * 64 + jl) * 64 + b];
                }
            }
            size_t gc = (size_t)t * 64 + b;
            float gr = giT[(size_t)j * NC + gc];
            float gz = giT[(size_t)(Lsz + j) * NC + gc];
            float gn = giT[(size_t)(2 * Lsz + j) * NC + gc];
            float hp = (step > 0) ? hT[((size_t)tp * Lsz + j) * Bsz + b] : 0.f;
            float r = sigf(gr + gh[0] + bhh[j]);
            float z = sigf(gz + gh[1] + bhh[Lsz + j]);
            float n = tanhf(gn + r * (gh[2] + bhh[2 * Lsz + j]));
            hT[((size_t)t * Lsz + j) * Bsz + b] = (1.f - z) * n + z * hp;
        }
    } else {
        int g2 = bid - 128;
        int i = g2 >> 3; int rest = g2 & 7;
        int jg = rest >> 2, q = rest & 3;
        const float* bih = bihAll + (size_t)i * R3sz;
        const float* bhh = bhhAll + (size_t)i * R3sz;
        const float* p0 = pgen + ((((size_t)i * 2 + 0) * 2 + jg) * 192) * 64;
        const float* p1 = pgen + ((((size_t)i * 2 + 1) * 2 + jg) * 192) * 64;
#pragma unroll
        for (int u = 0; u < 4; u++) {
            int jl = q * 16 + u * 4 + (tid >> 6);
            int j = jg * 64 + jl;
            float sih[3], shh[3];
#pragma unroll
            for (int g = 0; g < 3; g++) {
                sih[g] = p0[(size_t)(g * 64 + jl) * 64 + b];
                shh[g] = (step > 0) ? p1[(size_t)(g * 64 + jl) * 64 + b] : 0.f;
            }
            float r = sigf(sih[0] + bih[j] + shh[0] + bhh[j]);
            float z = sigf(sih[1] + bih[Rsz + j] + shh[1] + bhh[Rsz + j]);
            float n = tanhf(sih[2] + bih[2 * Rsz + j] + r * (shh[2] + bhh[2 * Rsz + j]));
            float hp = (step > 0) ? hprevT[((size_t)i * Rsz + j) * Bsz + b] : 0.f;
            float h = (1.f - z) * n + z * hp;
            size_t idx = ((size_t)i * Rsz + j) * Bsz + b;
            hcurT[idx] = h;
            hmaxT[idx] = (step == 0) ? h : fmaxf(hmaxT[idx], h);
        }
    }
}

// =====================================================================
// txt = (hf+hb)/2 -> row-major txt [b][t][c] AND column txtT [c][t*64+b].
// grid (32, 16).
// =====================================================================
__global__ __launch_bounds__(256) void txt_combine(
    const float* __restrict__ hfT, const float* __restrict__ hbT,
    float* __restrict__ txt, float* __restrict__ txtT)
{
    __shared__ float s[64][65];
    int t = blockIdx.x;
    int c0 = blockIdx.y * 64;
    int tid = threadIdx.x;
#pragma unroll
    for (int l = 0; l < 16; l++) {
        int e = l * 256 + tid;
        int cc = e >> 6, b = e & 63;
        size_t idx = ((size_t)t * Lsz + c0 + cc) * Bsz + b;
        s[cc][b] = 0.5f * (hfT[idx] + hbT[idx]);
    }
    __syncthreads();
#pragma unroll
    for (int l = 0; l < 16; l++) {
        int e = l * 256 + tid;
        int b = e >> 6, cc = e & 63;
        txt[((size_t)b * Tsz + t) * Lsz + c0 + cc] = s[cc][b];
    }
#pragma unroll
    for (int l = 0; l < 16; l++) {
        int e = l * 256 + tid;
        int cc = e >> 6, b = e & 63;
        txtT[(size_t)(c0 + cc) * NC + t * 64 + b] = s[cc][b];
    }
}

// =====================================================================
// Self-attention. v comes as 4 K-split partials vP[z][c][t*64+b];
// this kernel sums them + bias while staging. grid (64, 8).
// =====================================================================
__global__ __launch_bounds__(256) void attn_kernel(
    const float* __restrict__ q, const float* __restrict__ kmat,
    const float* __restrict__ vP, const float* __restrict__ sa_bv,
    const float* __restrict__ txt,
    const float* __restrict__ gamma_p, float* __restrict__ xattn)
{
    __shared__ float qs[32][129];
    __shared__ float ks[32][129];
    __shared__ float Sc[32][33];
    __shared__ float vs[128][33];
    int b = blockIdx.x;
    int c0 = blockIdx.y * 128;
    int tid = threadIdx.x;
    for (int e = tid; e < Tsz * Rsz; e += 256) {
        qs[e >> 7][e & 127] = q[(size_t)b * Tsz * Rsz + e];
        ks[e >> 7][e & 127] = kmat[(size_t)b * Tsz * Rsz + e];
    }
    // stage v tile: vs[cc][ss] = sum_z vP[z][(c0+cc)*NC + ss*64 + b] + bv
    for (int e = tid; e < 128 * 32; e += 256) {
        int cc = e >> 5, ss = e & 31;
        size_t base = (size_t)(c0 + cc) * NC + ss * 64 + b;
        float v = sa_bv[c0 + cc];
#pragma unroll
        for (int z = 0; z < 4; z++)
            v += vP[(size_t)z * Lsz * NC + base];
        vs[cc][ss] = v;
    }
    __syncthreads();
    for (int e = tid; e < Tsz * Tsz; e += 256) {
        int t = e >> 5, ss = e & 31;
        float acc = 0.f;
#pragma unroll 4
        for (int o = 0; o < Rsz; o++) acc = fmaf(qs[t][o], ks[ss][o], acc);
        Sc[t][ss] = acc;
    }
    __syncthreads();
    if (tid < 32) {
        int t = tid;
        float mx = -1e30f;
#pragma unroll
        for (int ss = 0; ss < 32; ss++) mx = fmaxf(mx, Sc[t][ss]);
        float sum = 0.f;
        float ex[32];
#pragma unroll
        for (int ss = 0; ss < 32; ss++) { ex[ss] = __expf(Sc[t][ss] - mx); sum += ex[ss]; }
        float inv = 1.f / sum;
#pragma unroll
        for (int ss = 0; ss < 32; ss++) Sc[t][ss] = ex[ss] * inv;
    }
    __syncthreads();
    float gamma = *gamma_p;
    for (int e = tid; e < Tsz * 128; e += 256) {
        int tt = e >> 7, cc = e & 127;
        float acc = 0.f;
#pragma unroll 8
        for (int ss = 0; ss < Tsz; ss++)
            acc = fmaf(Sc[tt][ss], vs[cc][ss], acc);
        size_t oidx = ((size_t)b * Tsz + tt) * Lsz + c0 + cc;
        xattn[oidx] = gamma * acc + txt[oidx];
    }
}

// ---------------- length-masked mean pool, grid (64,4) ----------------
__global__ __launch_bounds__(256) void pool_kernel(
    const float* __restrict__ xattn, const int* __restrict__ lens,
    float* __restrict__ txt_embed)
{
    int b = blockIdx.x;
    int c = blockIdx.y * 256 + threadIdx.x;
    int len = lens[b];
    float s = 0.f;
    for (int t = 0; t < len; t++) s += xattn[((size_t)b * Tsz + t) * Lsz + c];
    txt_embed[(size_t)b * Lsz + c] = s / (float)len;
}

// =====================================================================
// base_fcT[n][b] = dot(txt_emb[b][:], W_txt_fc[n][0:1024]). grid 256.
// =====================================================================
__global__ __launch_bounds__(256) void basefc_kernel(
    const float* __restrict__ temb, const float* __restrict__ W,
    float* __restrict__ outT)
{
    int lane = threadIdx.x & 63, w = threadIdx.x >> 6;
    int n = blockIdx.x * 4 + w;
    const float* wr = W + (size_t)n * (Rsz + Lsz) + lane * 16;
    float wv[16];
#pragma unroll
    for (int u = 0; u < 4; u++) *(float4*)&wv[u * 4] = *(const float4*)&wr[u * 4];
    for (int b = 0; b < Bsz; b++) {
        const float* te = temb + (size_t)b * Lsz + lane * 16;
        float tv[16];
#pragma unroll
        for (int u = 0; u < 4; u++) *(float4*)&tv[u * 4] = *(const float4*)&te[u * 4];
        float a = 0.f;
#pragma unroll
        for (int u = 0; u < 16; u++) a = fmaf(wv[u], tv[u], a);
#pragma unroll
        for (int off = 32; off; off >>= 1) a += __shfl_down(a, off, 64);
        if (lane == 0) outT[(size_t)n * Bsz + b] = a;
    }
}

// ---- hmaxT [i][j][b] -> hstdT [j][i*64+b], coalesced permute. grid 64 ----
__global__ __launch_bounds__(256) void hstdT_kernel(
    const float* __restrict__ hmaxT, float* __restrict__ hstdT)
{
    int i = blockIdx.x, tid = threadIdx.x;
    int b = tid & 63, j0 = tid >> 6;
#pragma unroll
    for (int l = 0; l < 32; l++) {
        int j = l * 4 + j0;
        hstdT[(size_t)j * 4096 + i * 64 + b] = hmaxT[((size_t)i * Rsz + j) * Bsz + b];
    }
}

// =====================================================================
// sims partial reduce: column layouts, fully coalesced. grid (64, 4).
// accA/accB are fp32 accumulators (pre-zeroed).
// =====================================================================
__global__ __launch_bounds__(256) void sims_part(
    const float* __restrict__ fcT, const float* __restrict__ base_fcT,
    const float* __restrict__ bfc, const float* __restrict__ iv,
    float* __restrict__ accA, float* __restrict__ accB)
{
    int i = blockIdx.x, cs = blockIdx.y;
    int tid = threadIdx.x;
    int w = tid >> 6, b = tid & 63;
    float s1 = 0.f, s2 = 0.f;
    for (int u = 0; u < 64; u++) {
        int c = cs * 256 + w * 64 + u;
        float f = fcT[(size_t)c * 4096 + i * 64 + b] + base_fcT[(size_t)c * Bsz + b] + bfc[c];
        s1 = fmaf(f, f, s1);
        s2 = fmaf(f, iv[(size_t)i * Lsz + c], s2);
    }
    int m = i * 64 + b;
    atomicAdd(&accA[m], s1);
    atomicAdd(&accB[m], s2);
}

__global__ __launch_bounds__(256) void sims_final(
    const float* __restrict__ accA, const float* __restrict__ accB,
    float* __restrict__ out)
{
    int m = blockIdx.x * 256 + threadIdx.x;
    out[m] = accB[m] / (sqrtf(accA[m]) + 1e-8f);
}

// =====================================================================
extern "C" void kernel_launch(void* const* d_in, const int* in_sizes, int n_in,
                              void* d_out, int out_size, void* d_ws, size_t ws_size,
                              hipStream_t stream)
{
    const float* img_embed    = (const float*)d_in[0];
    const float* cap_embed    = (const float*)d_in[1];
    const int*   lens         = (const int*)d_in[2];
    const float* W_reduce_img = (const float*)d_in[3];
    const float* b_reduce_img = (const float*)d_in[4];
    const float* W_reduce_txt = (const float*)d_in[5];
    const float* b_reduce_txt = (const float*)d_in[6];
    const float* gru_Wih_f    = (const float*)d_in[7];
    const float* gru_Whh_f    = (const float*)d_in[8];
    const float* gru_bih_f    = (const float*)d_in[9];
    const float* gru_bhh_f    = (const float*)d_in[10];
    const float* gru_Wih_b    = (const float*)d_in[11];
    const float* gru_Whh_b    = (const float*)d_in[12];
    const float* gru_bih_b    = (const float*)d_in[13];
    const float* gru_bhh_b    = (const float*)d_in[14];
    const float* sa_Wq        = (const float*)d_in[15];
    const float* sa_bq        = (const float*)d_in[16];
    const float* sa_Wk        = (const float*)d_in[17];
    const float* sa_bk        = (const float*)d_in[18];
    const float* sa_Wv        = (const float*)d_in[19];
    const float* sa_bv        = (const float*)d_in[20];
    const float* sa_gamma     = (const float*)d_in[21];
    const float* gen_Wih      = (const float*)d_in[22];
    const float* gen_bih      = (const float*)d_in[23];
    const float* gen_Whh      = (const float*)d_in[24];
    const float* gen_bhh      = (const float*)d_in[25];
    const float* gen_Wbih     = (const float*)d_in[26];
    const float* gen_bbih     = (const float*)d_in[27];
    const float* gen_Wbhh     = (const float*)d_in[28];
    const float* gen_bbhh     = (const float*)d_in[29];
    const float* W_txt_fc     = (const float*)d_in[30];
    const float* b_txt_fc     = (const float*)d_in[31];

    float* ws = (float*)d_ws;
    size_t off = 0;
    auto alloc = [&](size_t n) { float* p = ws + off; off += n; return p; };
    float* giT2_b   = alloc((size_t)H3sz * NC);
    float* hfT      = alloc((size_t)Tsz * Lsz * Bsz);
    float* hbT      = alloc((size_t)Tsz * Lsz * Bsz);
    float* capTr    = alloc((size_t)KPAD * NC);
    float* capT2    = alloc((size_t)Rsz * NC);
    float* txt      = alloc((size_t)Bsz * Tsz * Lsz);
    float* txtT     = alloc((size_t)Lsz * NC);
    float* qbuf     = alloc((size_t)Bsz * Tsz * Rsz);
    float* kbuf     = alloc((size_t)Bsz * Tsz * Rsz);
    float* vP       = alloc((size_t)4 * Lsz * NC);       // 4 K-split partials
    float* xattn    = alloc((size_t)Bsz * Tsz * Lsz);
    float* txt_emb  = alloc((size_t)Bsz * Lsz);
    float* base     = alloc((size_t)Bsz * Rsz);
    float* iv       = alloc((size_t)Bsz * Lsz);
    float* WihAll   = alloc((size_t)Bsz * GENROWS);
    float* WhhAll   = alloc((size_t)Bsz * GENROWS);
    float* WihAllT  = alloc((size_t)Bsz * GENROWS);
    float* WhhAllT  = alloc((size_t)Bsz * GENROWS);
    float* WhhT_f   = alloc((size_t)Lsz * H3sz);
    float* WhhT_b   = alloc((size_t)Lsz * H3sz);
    float* WihT_f   = alloc((size_t)KPAD * H3sz);
    float* WihT_b   = alloc((size_t)KPAD * H3sz);
    float* WrtT     = alloc((size_t)KPAD * Rsz);
    float* WvT      = alloc((size_t)Lsz * Lsz);
    float* WfcT     = alloc((size_t)Rsz * Lsz);
    float* bihAll   = alloc((size_t)Bsz * R3sz);
    float* bhhAll   = alloc((size_t)Bsz * R3sz);
    float* hA       = alloc((size_t)Bsz * Rsz * Bsz);
    float* hB       = alloc((size_t)Bsz * Rsz * Bsz);
    float* hmaxT    = alloc((size_t)Bsz * Rsz * Bsz);
    float* hstdT    = alloc((size_t)Rsz * Bsz * Bsz);
    float* base_fcT = alloc((size_t)Lsz * Bsz);
    float* fcT      = alloc((size_t)Lsz * Bsz * Bsz);    // [1024][4096]
    float* accA     = alloc(4096);
    float* accB     = alloc(4096);
    // Aliases (disjoint lifetimes):
    float* giT2_f = WihAll;   // raw gen weights dead after trans_gen
    float* pcap = fcT;        // 3.15M floats in fcT (4.19M); fcT written later
    float* pgen = vP;         // 3.15M floats in vP (8.4M); vP written later

    // 0) zero the sims accumulators
    hipMemsetAsync(accA, 0, 2 * 4096 * sizeof(float), stream);

    // 1) one-time transposes
    transp_kernel<<<dim3(16, 48), 256, 0, stream>>>(gru_Whh_f, WhhT_f, H3sz, Lsz, Lsz, Lsz, 0);
    transp_kernel<<<dim3(16, 48), 256, 0, stream>>>(gru_Whh_b, WhhT_b, H3sz, Lsz, Lsz, Lsz, 0);
    transp_kernel<<<dim3(5, 48), 256, 0, stream>>>(gru_Wih_f, WihT_f, H3sz, DIN, KPAD, DIN, 0);
    transp_kernel<<<dim3(5, 48), 256, 0, stream>>>(gru_Wih_b, WihT_b, H3sz, DIN, KPAD, DIN, 0);
    transp_kernel<<<dim3(5, 2), 256, 0, stream>>>(W_reduce_txt, WrtT, Rsz, DIN, KPAD, DIN, 0);
    transp_kernel<<<dim3(16, 16), 256, 0, stream>>>(sa_Wv, WvT, Lsz, Lsz, Lsz, Lsz, 0);
    transp_kernel<<<dim3(2, 16), 256, 0, stream>>>(W_txt_fc, WfcT, Lsz, Rsz, Rsz, Rsz + Lsz, Lsz);
    captr_kernel<<<dim3(32, 5), 256, 0, stream>>>(cap_embed, capTr);

    // 2) image-side precompute + generated weights (+ transposes)
    img_kernel<<<64, 256, 0, stream>>>(img_embed, W_reduce_img, b_reduce_img, base, iv);
    genw_kernel<<<dim3(194, 2), 256, 0, stream>>>(gen_Wih, gen_bih, gen_Whh, gen_bhh,
        gen_Wbih, gen_bbih, gen_Wbhh, gen_bbhh, base, WihAll, WhhAll, bihAll, bhhAll);
    trans_gen<<<dim3(2, 6, 128), 256, 0, stream>>>(WihAll, WhhAll, WihAllT, WhhAllT);

    // 3) gi (both dirs) + cap_reduced (after trans_gen: giT2_f aliases raw gen W)
    gemm_tt<<<dim3(16, 24, 2), 256, 0, stream>>>(WihT_f, WihT_b, capTr,
        gru_bih_f, gru_bih_b, giT2_f, giT2_b, H3sz);
    gemm_tt<<<dim3(16, 1, 1), 256, 0, stream>>>(WrtT, WrtT, capTr,
        b_reduce_txt, b_reduce_txt, capT2, capT2, Rsz);

    // 4) recurrences
    for (int s = 0; s < Tsz; s++) {
        const float* hp = (s & 1) ? hA : hB;   // unused at s==0
        float* hc = (s & 1) ? hB : hA;
        if (s == 0) hp = hA;
        step_gemm2<<<512, 256, 0, stream>>>(hfT, hbT, WhhT_f, WhhT_b,
            capT2, WihAllT, WhhAllT, hp, pcap, pgen, s);
        step_gates2<<<640, 256, 0, stream>>>(pcap, pgen, giT2_f, giT2_b, hfT, hbT,
            gru_bhh_f, gru_bhh_b, bihAll, bhhAll, hp, hc, hmaxT, s);
    }
    hstdT_kernel<<<64, 256, 0, stream>>>(hmaxT, hstdT);

    // 5) combine + self-attention (v via K-split TT GEMM)
    txt_combine<<<dim3(32, 16), 256, 0, stream>>>(hfT, hbT, txt, txtT);
    gemm_bias<<<dim3(2, 32, 2), 256, 0, stream>>>(txt, Lsz, sa_Wq, sa_Wk, Lsz, 0,
        sa_bq, sa_bk, qbuf, kbuf, Bsz * Tsz, Rsz, Lsz);
    gemm_ttp<<<dim3(16, 8, 4), 256, 0, stream>>>(WvT, txtT, vP, Lsz, NC, 256);
    attn_kernel<<<dim3(64, 8), 256, 0, stream>>>(qbuf, kbuf, vP, sa_bv, txt,
        sa_gamma, xattn);

    // 6) pool + image-independent FC part (transposed output)
    pool_kernel<<<dim3(64, 4), 256, 0, stream>>>(xattn, lens, txt_emb);
    basefc_kernel<<<256, 256, 0, stream>>>(txt_emb, W_txt_fc, base_fcT);

    // 7) fc delta (column layout) + sims partial/final
    gemm_ttp<<<dim3(32, 8, 1), 256, 0, stream>>>(WfcT, hstdT, fcT, Lsz, 4096, Rsz);
    sims_part<<<dim3(64, 4), 256, 0, stream>>>(fcT, base_fcT, b_txt_fc, iv, accA, accB);
    sims_final<<<16, 256, 0, stream>>>(accA, accB, (float*)d_out);
}

// Round 10
// 1910.158 us; speedup vs baseline: 1.1131x; 1.1131x over previous
//
#include <hip/hip_runtime.h>
#include <math.h>

// ---------------- problem constants ----------------
#define Lsz   1024
#define Tsz   32
#define Bsz   64
#define DIN   300
#define REG   36
#define Rsz   128
#define R3sz  384
#define H3sz  3072
#define GENROWS 49152   // R3sz * Rsz
#define NC    2048      // caption columns c = t*64 + b
#define KPAD  304       // DIN padded to /16

__device__ __forceinline__ float sigf(float x) { return 1.f / (1.f + __expf(-x)); }

// =====================================================================
// Generic tiled SGEMM (64x64 tile, 4x4 reg tile), row-major C.
// z-dim selects a second problem. Used only for q/k projections now.
// =====================================================================
__global__ __launch_bounds__(256) void gemm_bias(
    const float* __restrict__ A, int lda,
    const float* __restrict__ W1, const float* __restrict__ W2, int ldw, int woff,
    const float* __restrict__ bias1, const float* __restrict__ bias2,
    float* __restrict__ C1, float* __restrict__ C2,
    int M, int N, int K)
{
    const float* W = blockIdx.z ? W2 : W1;
    const float* bias = blockIdx.z ? bias2 : bias1;
    float* C = blockIdx.z ? C2 : C1;
    __shared__ float As[16][68];
    __shared__ float Ws[16][68];
    int tid = threadIdx.x;
    int tx = tid & 15, ty = tid >> 4;
    int m0 = blockIdx.y * 64, n0 = blockIdx.x * 64;
    float acc[4][4];
#pragma unroll
    for (int i = 0; i < 4; i++)
#pragma unroll
        for (int j = 0; j < 4; j++) acc[i][j] = 0.f;

    for (int k0 = 0; k0 < K; k0 += 16) {
#pragma unroll
        for (int l = 0; l < 4; l++) {
            int e = l * 256 + tid;
            int kk = e & 15, mm = e >> 4;
            int m = m0 + mm, k = k0 + kk;
            As[kk][mm] = (m < M && k < K) ? A[(size_t)m * lda + k] : 0.f;
        }
#pragma unroll
        for (int l = 0; l < 4; l++) {
            int e = l * 256 + tid;
            int kk = e & 15, nn = e >> 4;
            int n = n0 + nn, k = k0 + kk;
            Ws[kk][nn] = (n < N && k < K) ? W[(size_t)n * ldw + woff + k] : 0.f;
        }
        __syncthreads();
#pragma unroll
        for (int kk = 0; kk < 16; kk++) {
            float4 a4 = *(const float4*)&As[kk][ty * 4];
            float4 w4 = *(const float4*)&Ws[kk][tx * 4];
            float av[4] = {a4.x, a4.y, a4.z, a4.w};
            float wv[4] = {w4.x, w4.y, w4.z, w4.w};
#pragma unroll
            for (int i = 0; i < 4; i++)
#pragma unroll
                for (int j = 0; j < 4; j++) acc[i][j] = fmaf(av[i], wv[j], acc[i][j]);
        }
        __syncthreads();
    }
#pragma unroll
    for (int i = 0; i < 4; i++) {
        int m = m0 + ty * 4 + i;
        if (m >= M) continue;
#pragma unroll
        for (int j = 0; j < 4; j++) {
            int n = n0 + tx * 4 + j;
            if (n >= N) continue;
            C[(size_t)m * N + n] = acc[i][j] + (bias ? bias[n] : 0.f);
        }
    }
}

// =====================================================================
// Generic transpose: out[c*R + r] = in[r*lda + woff + c], c < Cin,
// zero-pad c in [Cin, Cpad). grid (ceil(Cpad/64), ceil(R/64)).
// =====================================================================
__global__ __launch_bounds__(256) void transp_kernel(
    const float* __restrict__ in, float* __restrict__ out,
    int R, int Cin, int Cpad, int lda, int woff)
{
    __shared__ float s[64][65];
    int c0 = blockIdx.x * 64, r0 = blockIdx.y * 64;
    int tid = threadIdx.x;
#pragma unroll
    for (int l = 0; l < 16; l++) {
        int e = l * 256 + tid;
        int rr = e >> 6, cc = e & 63;
        int r = r0 + rr, c = c0 + cc;
        s[rr][cc] = (r < R && c < Cin) ? in[(size_t)r * lda + woff + c] : 0.f;
    }
    __syncthreads();
#pragma unroll
    for (int l = 0; l < 16; l++) {
        int e = l * 256 + tid;
        int cc = e >> 6, rr = e & 63;
        int c = c0 + cc, r = r0 + rr;
        if (c < Cpad && r < R) out[(size_t)c * R + r] = s[rr][cc];
    }
}

// =====================================================================
// cap_embed [b][t][d] -> capTr [k][t*64+b], k zero-padded to 304.
// =====================================================================
__global__ __launch_bounds__(256) void captr_kernel(
    const float* __restrict__ cap_embed, float* __restrict__ capTr)
{
    __shared__ float s[64][65];
    int t = blockIdx.x, kc = blockIdx.y;
    int tid = threadIdx.x;
#pragma unroll
    for (int l = 0; l < 16; l++) {
        int e = l * 256 + tid;
        int b = e >> 6, kk = e & 63;
        int k = kc * 64 + kk;
        s[b][kk] = (k < DIN) ? cap_embed[((size_t)b * Tsz + t) * DIN + k] : 0.f;
    }
    __syncthreads();
#pragma unroll
    for (int l = 0; l < 16; l++) {
        int e = l * 256 + tid;
        int kk = e >> 6, b = e & 63;
        int k = kc * 64 + kk;
        if (k < KPAD)
            capTr[(size_t)k * NC + t * 64 + b] = s[b][kk];
    }
}

// =====================================================================
// All-transposed GEMM for gi: C[n][c] = sum_k WT[k][n]*X[k][c] + bias[n].
// WT [KPAD][Ntot], X [KPAD][NC]. Tile 128x128, 8x8 reg tile.
// =====================================================================
__global__ __launch_bounds__(256) void gemm_tt(
    const float* __restrict__ WT1, const float* __restrict__ WT2,
    const float* __restrict__ X,
    const float* __restrict__ b1, const float* __restrict__ b2,
    float* __restrict__ C1, float* __restrict__ C2, int Ntot)
{
    const float* WT = blockIdx.z ? WT2 : WT1;
    const float* bias = blockIdx.z ? b2 : b1;
    float* C = blockIdx.z ? C2 : C1;
    __shared__ float Ws[16][132];
    __shared__ float Xs[16][132];
    int tid = threadIdx.x, tx = tid & 15, ty = tid >> 4;
    int c0 = blockIdx.x * 128, n0 = blockIdx.y * 128;
    float acc[8][8];
#pragma unroll
    for (int i = 0; i < 8; i++)
#pragma unroll
        for (int j = 0; j < 8; j++) acc[i][j] = 0.f;

    for (int k0 = 0; k0 < KPAD; k0 += 16) {
#pragma unroll
        for (int l = 0; l < 2; l++) {
            int e = l * 256 + tid;
            int l16 = e & 15, seg = e >> 4;
            int kk = seg & 15, half = seg >> 4;
            int col = half * 64 + l16 * 4;
            *(float4*)&Ws[kk][col] = *(const float4*)&WT[(size_t)(k0 + kk) * Ntot + n0 + col];
            *(float4*)&Xs[kk][col] = *(const float4*)&X[(size_t)(k0 + kk) * NC + c0 + col];
        }
        __syncthreads();
#pragma unroll
        for (int kk = 0; kk < 16; kk++) {
            float a[8], x[8];
            *(float4*)&a[0] = *(const float4*)&Ws[kk][ty * 8];
            *(float4*)&a[4] = *(const float4*)&Ws[kk][ty * 8 + 4];
            *(float4*)&x[0] = *(const float4*)&Xs[kk][tx * 8];
            *(float4*)&x[4] = *(const float4*)&Xs[kk][tx * 8 + 4];
#pragma unroll
            for (int i = 0; i < 8; i++)
#pragma unroll
                for (int j = 0; j < 8; j++) acc[i][j] = fmaf(a[i], x[j], acc[i][j]);
        }
        __syncthreads();
    }
#pragma unroll
    for (int i = 0; i < 8; i++) {
        int n = n0 + ty * 8 + i;
        float bv = bias[n];
        *(float4*)&C[(size_t)n * NC + c0 + tx * 8] =
            make_float4(acc[i][0] + bv, acc[i][1] + bv, acc[i][2] + bv, acc[i][3] + bv);
        *(float4*)&C[(size_t)n * NC + c0 + tx * 8 + 4] =
            make_float4(acc[i][4] + bv, acc[i][5] + bv, acc[i][6] + bv, acc[i][7] + bv);
    }
}

// =====================================================================
// Parametrized TT GEMM with K-split: z selects k-range, separate partial
// buffer per z. WT [Ktot][Ntot], X [Ktot][ncols].
// =====================================================================
__global__ __launch_bounds__(256) void gemm_ttp(
    const float* __restrict__ WT, const float* __restrict__ X,
    float* __restrict__ C, int Ntot, int ncols, int klen)
{
    int z = blockIdx.z;
    int kbase = z * klen;
    float* Cp = C + (size_t)z * Ntot * ncols;
    __shared__ float Ws[16][132];
    __shared__ float Xs[16][132];
    int tid = threadIdx.x, tx = tid & 15, ty = tid >> 4;
    int c0 = blockIdx.x * 128, n0 = blockIdx.y * 128;
    float acc[8][8];
#pragma unroll
    for (int i = 0; i < 8; i++)
#pragma unroll
        for (int j = 0; j < 8; j++) acc[i][j] = 0.f;

    for (int k0 = 0; k0 < klen; k0 += 16) {
#pragma unroll
        for (int l = 0; l < 2; l++) {
            int e = l * 256 + tid;
            int l16 = e & 15, seg = e >> 4;
            int kk = seg & 15, half = seg >> 4;
            int col = half * 64 + l16 * 4;
            *(float4*)&Ws[kk][col] =
                *(const float4*)&WT[(size_t)(kbase + k0 + kk) * Ntot + n0 + col];
            *(float4*)&Xs[kk][col] =
                *(const float4*)&X[(size_t)(kbase + k0 + kk) * ncols + c0 + col];
        }
        __syncthreads();
#pragma unroll
        for (int kk = 0; kk < 16; kk++) {
            float a[8], x[8];
            *(float4*)&a[0] = *(const float4*)&Ws[kk][ty * 8];
            *(float4*)&a[4] = *(const float4*)&Ws[kk][ty * 8 + 4];
            *(float4*)&x[0] = *(const float4*)&Xs[kk][tx * 8];
            *(float4*)&x[4] = *(const float4*)&Xs[kk][tx * 8 + 4];
#pragma unroll
            for (int i = 0; i < 8; i++)
#pragma unroll
                for (int j = 0; j < 8; j++) acc[i][j] = fmaf(a[i], x[j], acc[i][j]);
        }
        __syncthreads();
    }
#pragma unroll
    for (int i = 0; i < 8; i++) {
        int n = n0 + ty * 8 + i;
        *(float4*)&Cp[(size_t)n * ncols + c0 + tx * 8] =
            make_float4(acc[i][0], acc[i][1], acc[i][2], acc[i][3]);
        *(float4*)&Cp[(size_t)n * ncols + c0 + tx * 8 + 4] =
            make_float4(acc[i][4], acc[i][5], acc[i][6], acc[i][7]);
    }
}

// =====================================================================
// Generated weights as a proper GEMM, emitting the TRANSPOSED layout
// [i][k][row] that step_gemm2 consumes (replaces genw_kernel+trans_gen).
// grid (3, 129, 2): x=row-tile (128 rows), y=k (0..127; y==128 -> the
// small Wbih/Wbhh bias-matrix path), z=matrix (0=ih, 1=hh).
// C[i][row] = sum_p gen_W[rowidx][p] * base[i][p] + gen_b[rowidx],
// rowidx = (r0+row)*128 + k  (normal) or r0+row (bias path).
// Tile M=64(i) x N=128(row), 4x8 reg tile, K=128 in chunks of 16.
// =====================================================================
__global__ __launch_bounds__(256) void genw_gemm(
    const float* __restrict__ gen_Wih, const float* __restrict__ gen_bih,
    const float* __restrict__ gen_Whh, const float* __restrict__ gen_bhh,
    const float* __restrict__ gen_Wbih, const float* __restrict__ gen_bbih,
    const float* __restrict__ gen_Wbhh, const float* __restrict__ gen_bbhh,
    const float* __restrict__ base,
    float* __restrict__ WihAllT, float* __restrict__ WhhAllT,
    float* __restrict__ bihAll, float* __restrict__ bhhAll)
{
    __shared__ float Bs[64][132];
    __shared__ float Ws[16][132];
    __shared__ float bs[128];
    int rtile = blockIdx.x, ky = blockIdx.y, mat = blockIdx.z;
    int r0 = rtile * 128;
    bool normal = (ky < 128);
    int k = normal ? ky : 0;
    const float* W  = normal ? (mat ? gen_Whh : gen_Wih) : (mat ? gen_Wbhh : gen_Wbih);
    const float* bi = normal ? (mat ? gen_bhh : gen_bih) : (mat ? gen_bbhh : gen_bbih);
    float* out      = normal ? (mat ? WhhAllT : WihAllT) : (mat ? bhhAll : bihAll);
    int rowmul = normal ? 128 : 1;
    size_t ostride = normal ? (size_t)GENROWS : (size_t)R3sz;
    size_t obase   = normal ? (size_t)k * R3sz + r0 : (size_t)r0;

    int tid = threadIdx.x, tx = tid & 15, ty = tid >> 4;
    // stage base [64][128] -> Bs (pad 132)
#pragma unroll
    for (int l = 0; l < 8; l++) {
        int e = l * 256 + tid;
        int i = e >> 5, p4 = (e & 31) * 4;
        *(float4*)&Bs[i][p4] = *(const float4*)&base[(size_t)i * Rsz + p4];
    }
    if (tid < 128) bs[tid] = bi[(size_t)(r0 + tid) * rowmul + k];

    float acc[4][8];
#pragma unroll
    for (int i = 0; i < 4; i++)
#pragma unroll
        for (int j = 0; j < 8; j++) acc[i][j] = 0.f;

    for (int c = 0; c < 8; c++) {
        int p0 = c * 16;
        // stage W chunk: Ws[pp][rr], f4 global loads
#pragma unroll
        for (int l = 0; l < 2; l++) {
            int e = l * 256 + tid;
            int rr = e >> 2, pq = (e & 3) * 4;
            size_t rowidx = (size_t)(r0 + rr) * rowmul + k;
            float4 v = *(const float4*)&W[rowidx * Rsz + p0 + pq];
            Ws[pq + 0][rr] = v.x;
            Ws[pq + 1][rr] = v.y;
            Ws[pq + 2][rr] = v.z;
            Ws[pq + 3][rr] = v.w;
        }
        __syncthreads();
#pragma unroll
        for (int kk = 0; kk < 16; kk++) {
            float a[4], b8[8];
#pragma unroll
            for (int ii = 0; ii < 4; ii++) a[ii] = Bs[ty * 4 + ii][p0 + kk];
            *(float4*)&b8[0] = *(const float4*)&Ws[kk][tx * 8];
            *(float4*)&b8[4] = *(const float4*)&Ws[kk][tx * 8 + 4];
#pragma unroll
            for (int ii = 0; ii < 4; ii++)
#pragma unroll
                for (int jj = 0; jj < 8; jj++)
                    acc[ii][jj] = fmaf(a[ii], b8[jj], acc[ii][jj]);
        }
        __syncthreads();
    }
#pragma unroll
    for (int ii = 0; ii < 4; ii++) {
        int i = ty * 4 + ii;
        float* op = out + (size_t)i * ostride + obase + tx * 8;
        *(float4*)&op[0] = make_float4(acc[ii][0] + bs[tx * 8 + 0], acc[ii][1] + bs[tx * 8 + 1],
                                       acc[ii][2] + bs[tx * 8 + 2], acc[ii][3] + bs[tx * 8 + 3]);
        *(float4*)&op[4] = make_float4(acc[ii][4] + bs[tx * 8 + 4], acc[ii][5] + bs[tx * 8 + 5],
                                       acc[ii][6] + bs[tx * 8 + 6], acc[ii][7] + bs[tx * 8 + 7]);
    }
}

// =====================================================================
// Fused image-side precompute. grid 64.
// =====================================================================
__global__ __launch_bounds__(256) void img_kernel(
    const float* __restrict__ img_embed, const float* __restrict__ W_reduce_img,
    const float* __restrict__ b_reduce_img,
    float* __restrict__ base, float* __restrict__ iv)
{
    int i = blockIdx.x;
    int tid = threadIdx.x;
    __shared__ float row[Lsz];
    __shared__ float ps[4];
    for (int c = tid; c < Lsz; c += 256) {
        float s = 0.f;
        for (int r = 0; r < REG; r++) s += img_embed[((size_t)i * REG + r) * Lsz + c];
        row[c] = s * (1.f / (float)REG);
    }
    __syncthreads();
    float ss = 0.f;
    for (int c = tid; c < Lsz; c += 256) { float x = row[c]; ss = fmaf(x, x, ss); }
#pragma unroll
    for (int off = 32; off; off >>= 1) ss += __shfl_down(ss, off, 64);
    int lane = tid & 63, w = tid >> 6;
    if (lane == 0) ps[w] = ss;
    __syncthreads();
    float inv = 1.f / (sqrtf(ps[0] + ps[1] + ps[2] + ps[3]) + 1e-8f);
    for (int c = tid; c < Lsz; c += 256)
        iv[(size_t)i * Lsz + c] = row[c] * inv;
    for (int o = w * 32; o < w * 32 + 32; o++) {
        float a = 0.f;
        const float* wr = W_reduce_img + (size_t)o * Lsz + lane * 16;
        const float* rr = row + lane * 16;
#pragma unroll
        for (int u = 0; u < 16; u++) a = fmaf(wr[u], rr[u], a);
#pragma unroll
        for (int off = 32; off; off >>= 1) a += __shfl_down(a, off, 64);
        if (lane == 0) base[(size_t)i * Rsz + o] = a + b_reduce_img[o];
    }
}

// =====================================================================
// Recurrence phase A, K-chunk 32. grid 512 x 256 thr.
// =====================================================================
__global__ __launch_bounds__(256) void step_gemm2(
    const float* __restrict__ hfT, const float* __restrict__ hbT,
    const float* __restrict__ WhhT_f, const float* __restrict__ WhhT_b,
    const float* __restrict__ capT2,
    const float* __restrict__ WihAllT, const float* __restrict__ WhhAllT,
    const float* __restrict__ hprevT,
    float* __restrict__ pcap, float* __restrict__ pgen, int step)
{
    __shared__ float As[32][196];
    __shared__ float Hs[32][68];
    int tid = threadIdx.x;
    int tx = tid & 15, ty = tid >> 4;
    int bid = blockIdx.x;

    const float* WT; const float* X; float* P;
    int ldn, gstride, jg, kbase;
    size_t xstride;

    if (bid < 256) {
        if (step == 0) return;
        int dir = bid >> 7; int rem = bid & 127;
        jg = rem >> 3; int ks = rem & 7;
        WT = dir ? WhhT_b : WhhT_f;        // [1024][3072]
        kbase = ks * 128;
        const float* hT = dir ? hbT : hfT;
        int t  = dir ? (Tsz - 1 - step) : step;
        int tp = dir ? (t + 1) : (t - 1);
        X = hT + ((size_t)tp * Lsz + ks * 128) * Bsz;
        xstride = Bsz;
        P = pcap + ((((size_t)dir * 8 + ks) * 16 + jg) * 192) * 64;
        ldn = H3sz; gstride = Lsz;
    } else {
        int g = bid - 256;
        int x = g & 7, rest = g >> 3;
        int i = x + 8 * (rest >> 2);
        int sub = rest & 3; int ks = sub >> 1; jg = sub & 1;
        if (ks == 1 && step == 0) return;
        WT = (ks ? WhhAllT : WihAllT) + (size_t)i * GENROWS;   // [128][384]
        kbase = 0;
        if (ks) { X = hprevT + (size_t)i * Rsz * Bsz; xstride = Bsz; }
        else    { X = capT2 + (size_t)step * 64;      xstride = NC;  }
        P = pgen + ((((size_t)i * 2 + ks) * 2 + jg) * 192) * 64;
        ldn = R3sz; gstride = Rsz;
    }

    float acc[12][4];
#pragma unroll
    for (int i = 0; i < 12; i++)
#pragma unroll
        for (int j = 0; j < 4; j++) acc[i][j] = 0.f;

    for (int c = 0; c < 4; c++) {
        int k0 = c * 32;
#pragma unroll
        for (int l = 0; l < 6; l++) {
            int e = l * 256 + tid;
            int l16 = e & 15, seg = e >> 4;        // seg < 96
            int kk = seg & 31, gate = seg >> 5;    // gate in 0..2
            const float* src = WT + (size_t)(kbase + k0 + kk) * ldn
                               + gate * gstride + jg * 64 + l16 * 4;
            *(float4*)&As[kk][gate * 64 + l16 * 4] = *(const float4*)src;
        }
#pragma unroll
        for (int l = 0; l < 2; l++) {
            int e = l * 256 + tid;
            int l16 = e & 15, kk = e >> 4;         // kk < 32
            *(float4*)&Hs[kk][l16 * 4] =
                *(const float4*)&X[(size_t)(k0 + kk) * xstride + l16 * 4];
        }
        __syncthreads();
#pragma unroll
        for (int kk = 0; kk < 32; kk++) {
            float a[12], hb[4];
            *(float4*)&a[0] = *(const float4*)&As[kk][ty * 12];
            *(float4*)&a[4] = *(const float4*)&As[kk][ty * 12 + 4];
            *(float4*)&a[8] = *(const float4*)&As[kk][ty * 12 + 8];
            *(float4*)&hb[0] = *(const float4*)&Hs[kk][tx * 4];
#pragma unroll
            for (int i = 0; i < 12; i++)
#pragma unroll
                for (int j = 0; j < 4; j++) acc[i][j] = fmaf(a[i], hb[j], acc[i][j]);
        }
        __syncthreads();
    }
#pragma unroll
    for (int i = 0; i < 12; i++) {
        int mm = ty * 12 + i;
        *(float4*)&P[(size_t)mm * 64 + tx * 4] =
            make_float4(acc[i][0], acc[i][1], acc[i][2], acc[i][3]);
    }
}

// =====================================================================
// Recurrence phase B: reduce K-slices + gates. grid 640 x 256.
// =====================================================================
__global__ __launch_bounds__(256) void step_gates2(
    const float* __restrict__ pcap, const float* __restrict__ pgen,
    const float* __restrict__ giT2_f, const float* __restrict__ giT2_b,
    float* __restrict__ hfT, float* __restrict__ hbT,
    const float* __restrict__ bhh_f, const float* __restrict__ bhh_b,
    const float* __restrict__ bihAll, const float* __restrict__ bhhAll,
    const float* __restrict__ hprevT, float* __restrict__ hcurT,
    float* __restrict__ hmaxT, int step)
{
    int tid = threadIdx.x;
    int b = tid & 63;
    int bid = blockIdx.x;
    if (bid < 128) {
        int dir = bid >> 6; int rem = bid & 63;
        int jg = rem >> 2, q = rem & 3;
        const float* giT = dir ? giT2_b : giT2_f;
        float* hT        = dir ? hbT   : hfT;
        const float* bhh = dir ? bhh_b : bhh_f;
        int t  = dir ? (Tsz - 1 - step) : step;
        int tp = dir ? (t + 1) : (t - 1);
#pragma unroll
        for (int u = 0; u < 4; u++) {
            int jl = q * 16 + u * 4 + (tid >> 6);
            int j = jg * 64 + jl;
            float gh[3] = {0.f, 0.f, 0.f};
            if (step > 0) {
#pragma unroll
                for (int ks = 0; ks < 8; ks++) {
                    const float* pb = pcap + ((((size_t)dir * 8 + ks) * 16 + jg) * 192) * 64;
#pragma unroll
                    for (int g = 0; g < 3; g++)
                        gh[g] += pb[(size_t)(g * 64 + jl) * 64 + b];
                }
            }
            size_t gc = (size_t)t * 64 + b;
            float gr = giT[(size_t)j * NC + gc];
            float gz = giT[(size_t)(Lsz + j) * NC + gc];
            float gn = giT[(size_t)(2 * Lsz + j) * NC + gc];
            float hp = (step > 0) ? hT[((size_t)tp * Lsz + j) * Bsz + b] : 0.f;
            float r = sigf(gr + gh[0] + bhh[j]);
            float z = sigf(gz + gh[1] + bhh[Lsz + j]);
            float n = tanhf(gn + r * (gh[2] + bhh[2 * Lsz + j]));
            hT[((size_t)t * Lsz + j) * Bsz + b] = (1.f - z) * n + z * hp;
        }
    } else {
        int g2 = bid - 128;
        int i = g2 >> 3; int rest = g2 & 7;
        int jg = rest >> 2, q = rest & 3;
        const float* bih = bihAll + (size_t)i * R3sz;
        const float* bhh = bhhAll + (size_t)i * R3sz;
        const float* p0 = pgen + ((((size_t)i * 2 + 0) * 2 + jg) * 192) * 64;
        const float* p1 = pgen + ((((size_t)i * 2 + 1) * 2 + jg) * 192) * 64;
#pragma unroll
        for (int u = 0; u < 4; u++) {
            int jl = q * 16 + u * 4 + (tid >> 6);
            int j = jg * 64 + jl;
            float sih[3], shh[3];
#pragma unroll
            for (int g = 0; g < 3; g++) {
                sih[g] = p0[(size_t)(g * 64 + jl) * 64 + b];
                shh[g] = (step > 0) ? p1[(size_t)(g * 64 + jl) * 64 + b] : 0.f;
            }
            float r = sigf(sih[0] + bih[j] + shh[0] + bhh[j]);
            float z = sigf(sih[1] + bih[Rsz + j] + shh[1] + bhh[Rsz + j]);
            float n = tanhf(sih[2] + bih[2 * Rsz + j] + r * (shh[2] + bhh[2 * Rsz + j]));
            float hp = (step > 0) ? hprevT[((size_t)i * Rsz + j) * Bsz + b] : 0.f;
            float h = (1.f - z) * n + z * hp;
            size_t idx = ((size_t)i * Rsz + j) * Bsz + b;
            hcurT[idx] = h;
            hmaxT[idx] = (step == 0) ? h : fmaxf(hmaxT[idx], h);
        }
    }
}

// =====================================================================
// txt = (hf+hb)/2 -> row-major txt [b][t][c] AND column txtT [c][t*64+b].
// grid (32, 16).
// =====================================================================
__global__ __launch_bounds__(256) void txt_combine(
    const float* __restrict__ hfT, const float* __restrict__ hbT,
    float* __restrict__ txt, float* __restrict__ txtT)
{
    __shared__ float s[64][65];
    int t = blockIdx.x;
    int c0 = blockIdx.y * 64;
    int tid = threadIdx.x;
#pragma unroll
    for (int l = 0; l < 16; l++) {
        int e = l * 256 + tid;
        int cc = e >> 6, b = e & 63;
        size_t idx = ((size_t)t * Lsz + c0 + cc) * Bsz + b;
        s[cc][b] = 0.5f * (hfT[idx] + hbT[idx]);
    }
    __syncthreads();
#pragma unroll
    for (int l = 0; l < 16; l++) {
        int e = l * 256 + tid;
        int b = e >> 6, cc = e & 63;
        txt[((size_t)b * Tsz + t) * Lsz + c0 + cc] = s[cc][b];
    }
#pragma unroll
    for (int l = 0; l < 16; l++) {
        int e = l * 256 + tid;
        int cc = e >> 6, b = e & 63;
        txtT[(size_t)(c0 + cc) * NC + t * 64 + b] = s[cc][b];
    }
}

// =====================================================================
// Self-attention. v comes as 2 K-split partials vP[z][c][t*64+b];
// summed + bias while staging. grid (64, 8).
// =====================================================================
__global__ __launch_bounds__(256) void attn_kernel(
    const float* __restrict__ q, const float* __restrict__ kmat,
    const float* __restrict__ vP, const float* __restrict__ sa_bv,
    const float* __restrict__ txt,
    const float* __restrict__ gamma_p, float* __restrict__ xattn)
{
    __shared__ float qs[32][129];
    __shared__ float ks[32][129];
    __shared__ float Sc[32][33];
    __shared__ float vs[128][33];
    int b = blockIdx.x;
    int c0 = blockIdx.y * 128;
    int tid = threadIdx.x;
    for (int e = tid; e < Tsz * Rsz; e += 256) {
        qs[e >> 7][e & 127] = q[(size_t)b * Tsz * Rsz + e];
        ks[e >> 7][e & 127] = kmat[(size_t)b * Tsz * Rsz + e];
    }
    for (int e = tid; e < 128 * 32; e += 256) {
        int cc = e >> 5, ss = e & 31;
        size_t base = (size_t)(c0 + cc) * NC + ss * 64 + b;
        float v = sa_bv[c0 + cc];
#pragma unroll
        for (int z = 0; z < 2; z++)
            v += vP[(size_t)z * Lsz * NC + base];
        vs[cc][ss] = v;
    }
    __syncthreads();
    for (int e = tid; e < Tsz * Tsz; e += 256) {
        int t = e >> 5, ss = e & 31;
        float acc = 0.f;
#pragma unroll 4
        for (int o = 0; o < Rsz; o++) acc = fmaf(qs[t][o], ks[ss][o], acc);
        Sc[t][ss] = acc;
    }
    __syncthreads();
    if (tid < 32) {
        int t = tid;
        float mx = -1e30f;
#pragma unroll
        for (int ss = 0; ss < 32; ss++) mx = fmaxf(mx, Sc[t][ss]);
        float sum = 0.f;
        float ex[32];
#pragma unroll
        for (int ss = 0; ss < 32; ss++) { ex[ss] = __expf(Sc[t][ss] - mx); sum += ex[ss]; }
        float inv = 1.f / sum;
#pragma unroll
        for (int ss = 0; ss < 32; ss++) Sc[t][ss] = ex[ss] * inv;
    }
    __syncthreads();
    float gamma = *gamma_p;
    for (int e = tid; e < Tsz * 128; e += 256) {
        int tt = e >> 7, cc = e & 127;
        float acc = 0.f;
#pragma unroll 8
        for (int ss = 0; ss < Tsz; ss++)
            acc = fmaf(Sc[tt][ss], vs[cc][ss], acc);
        size_t oidx = ((size_t)b * Tsz + tt) * Lsz + c0 + cc;
        xattn[oidx] = gamma * acc + txt[oidx];
    }
}

// ---------------- length-masked mean pool, grid (64,4) ----------------
__global__ __launch_bounds__(256) void pool_kernel(
    const float* __restrict__ xattn, const int* __restrict__ lens,
    float* __restrict__ txt_embed)
{
    int b = blockIdx.x;
    int c = blockIdx.y * 256 + threadIdx.x;
    int len = lens[b];
    float s = 0.f;
    for (int t = 0; t < len; t++) s += xattn[((size_t)b * Tsz + t) * Lsz + c];
    txt_embed[(size_t)b * Lsz + c] = s / (float)len;
}

// =====================================================================
// base_fcT[n][b] = dot(txt_emb[b][:], W_txt_fc[n][0:1024]). grid 256.
// =====================================================================
__global__ __launch_bounds__(256) void basefc_kernel(
    const float* __restrict__ temb, const float* __restrict__ W,
    float* __restrict__ outT)
{
    int lane = threadIdx.x & 63, w = threadIdx.x >> 6;
    int n = blockIdx.x * 4 + w;
    const float* wr = W + (size_t)n * (Rsz + Lsz) + lane * 16;
    float wv[16];
#pragma unroll
    for (int u = 0; u < 4; u++) *(float4*)&wv[u * 4] = *(const float4*)&wr[u * 4];
    for (int b = 0; b < Bsz; b++) {
        const float* te = temb + (size_t)b * Lsz + lane * 16;
        float tv[16];
#pragma unroll
        for (int u = 0; u < 4; u++) *(float4*)&tv[u * 4] = *(const float4*)&te[u * 4];
        float a = 0.f;
#pragma unroll
        for (int u = 0; u < 16; u++) a = fmaf(wv[u], tv[u], a);
#pragma unroll
        for (int off = 32; off; off >>= 1) a += __shfl_down(a, off, 64);
        if (lane == 0) outT[(size_t)n * Bsz + b] = a;
    }
}

// ---- hmaxT [i][j][b] -> hstdT [j][i*64+b], coalesced permute. grid 64 ----
__global__ __launch_bounds__(256) void hstdT_kernel(
    const float* __restrict__ hmaxT, float* __restrict__ hstdT)
{
    int i = blockIdx.x, tid = threadIdx.x;
    int b = tid & 63, j0 = tid >> 6;
#pragma unroll
    for (int l = 0; l < 32; l++) {
        int j = l * 4 + j0;
        hstdT[(size_t)j * 4096 + i * 64 + b] = hmaxT[((size_t)i * Rsz + j) * Bsz + b];
    }
}

// =====================================================================
// sims partial reduce: column layouts, fully coalesced. grid (64, 4).
// =====================================================================
__global__ __launch_bounds__(256) void sims_part(
    const float* __restrict__ fcT, const float* __restrict__ base_fcT,
    const float* __restrict__ bfc, const float* __restrict__ iv,
    float* __restrict__ accA, float* __restrict__ accB)
{
    int i = blockIdx.x, cs = blockIdx.y;
    int tid = threadIdx.x;
    int w = tid >> 6, b = tid & 63;
    float s1 = 0.f, s2 = 0.f;
    for (int u = 0; u < 64; u++) {
        int c = cs * 256 + w * 64 + u;
        float f = fcT[(size_t)c * 4096 + i * 64 + b] + base_fcT[(size_t)c * Bsz + b] + bfc[c];
        s1 = fmaf(f, f, s1);
        s2 = fmaf(f, iv[(size_t)i * Lsz + c], s2);
    }
    int m = i * 64 + b;
    atomicAdd(&accA[m], s1);
    atomicAdd(&accB[m], s2);
}

__global__ __launch_bounds__(256) void sims_final(
    const float* __restrict__ accA, const float* __restrict__ accB,
    float* __restrict__ out)
{
    int m = blockIdx.x * 256 + threadIdx.x;
    out[m] = accB[m] / (sqrtf(accA[m]) + 1e-8f);
}

// =====================================================================
extern "C" void kernel_launch(void* const* d_in, const int* in_sizes, int n_in,
                              void* d_out, int out_size, void* d_ws, size_t ws_size,
                              hipStream_t stream)
{
    const float* img_embed    = (const float*)d_in[0];
    const float* cap_embed    = (const float*)d_in[1];
    const int*   lens         = (const int*)d_in[2];
    const float* W_reduce_img = (const float*)d_in[3];
    const float* b_reduce_img = (const float*)d_in[4];
    const float* W_reduce_txt = (const float*)d_in[5];
    const float* b_reduce_txt = (const float*)d_in[6];
    const float* gru_Wih_f    = (const float*)d_in[7];
    const float* gru_Whh_f    = (const float*)d_in[8];
    const float* gru_bih_f    = (const float*)d_in[9];
    const float* gru_bhh_f    = (const float*)d_in[10];
    const float* gru_Wih_b    = (const float*)d_in[11];
    const float* gru_Whh_b    = (const float*)d_in[12];
    const float* gru_bih_b    = (const float*)d_in[13];
    const float* gru_bhh_b    = (const float*)d_in[14];
    const float* sa_Wq        = (const float*)d_in[15];
    const float* sa_bq        = (const float*)d_in[16];
    const float* sa_Wk        = (const float*)d_in[17];
    const float* sa_bk        = (const float*)d_in[18];
    const float* sa_Wv        = (const float*)d_in[19];
    const float* sa_bv        = (const float*)d_in[20];
    const float* sa_gamma     = (const float*)d_in[21];
    const float* gen_Wih      = (const float*)d_in[22];
    const float* gen_bih      = (const float*)d_in[23];
    const float* gen_Whh      = (const float*)d_in[24];
    const float* gen_bhh      = (const float*)d_in[25];
    const float* gen_Wbih     = (const float*)d_in[26];
    const float* gen_bbih     = (const float*)d_in[27];
    const float* gen_Wbhh     = (const float*)d_in[28];
    const float* gen_bbhh     = (const float*)d_in[29];
    const float* W_txt_fc     = (const float*)d_in[30];
    const float* b_txt_fc     = (const float*)d_in[31];

    float* ws = (float*)d_ws;
    size_t off = 0;
    auto alloc = [&](size_t n) { float* p = ws + off; off += n; return p; };
    float* giT2_f   = alloc((size_t)H3sz * NC);
    float* giT2_b   = alloc((size_t)H3sz * NC);
    float* hfT      = alloc((size_t)Tsz * Lsz * Bsz);
    float* hbT      = alloc((size_t)Tsz * Lsz * Bsz);
    float* capTr    = alloc((size_t)KPAD * NC);
    float* capT2    = alloc((size_t)Rsz * NC);
    float* txt      = alloc((size_t)Bsz * Tsz * Lsz);
    float* txtT     = alloc((size_t)Lsz * NC);
    float* qbuf     = alloc((size_t)Bsz * Tsz * Rsz);
    float* kbuf     = alloc((size_t)Bsz * Tsz * Rsz);
    float* vP       = alloc((size_t)2 * Lsz * NC);       // 2 K-split partials
    float* xattn    = alloc((size_t)Bsz * Tsz * Lsz);
    float* txt_emb  = alloc((size_t)Bsz * Lsz);
    float* base     = alloc((size_t)Bsz * Rsz);
    float* iv       = alloc((size_t)Bsz * Lsz);
    float* WihAllT  = alloc((size_t)Bsz * GENROWS);      // [i][128][384]
    float* WhhAllT  = alloc((size_t)Bsz * GENROWS);
    float* WhhT_f   = alloc((size_t)Lsz * H3sz);
    float* WhhT_b   = alloc((size_t)Lsz * H3sz);
    float* WihT_f   = alloc((size_t)KPAD * H3sz);
    float* WihT_b   = alloc((size_t)KPAD * H3sz);
    float* WrtT     = alloc((size_t)KPAD * Rsz);
    float* WvT      = alloc((size_t)Lsz * Lsz);
    float* WfcT     = alloc((size_t)Rsz * Lsz);
    float* bihAll   = alloc((size_t)Bsz * R3sz);
    float* bhhAll   = alloc((size_t)Bsz * R3sz);
    float* hA       = alloc((size_t)Bsz * Rsz * Bsz);
    float* hB       = alloc((size_t)Bsz * Rsz * Bsz);
    float* hmaxT    = alloc((size_t)Bsz * Rsz * Bsz);
    float* hstdT    = alloc((size_t)Rsz * Bsz * Bsz);
    float* base_fcT = alloc((size_t)Lsz * Bsz);
    float* fcT      = alloc((size_t)Lsz * Bsz * Bsz);    // [1024][4096]
    float* accA     = alloc(4096);
    float* accB     = alloc(4096);
    // Aliases (disjoint lifetimes):
    float* pcap = fcT;        // 3.15M floats in fcT (4.19M); fcT written later
    float* pgen = vP;         // 3.15M floats in vP (4.19M); vP written later

    // 0) zero the sims accumulators
    hipMemsetAsync(accA, 0, 2 * 4096 * sizeof(float), stream);

    // 1) one-time transposes
    transp_kernel<<<dim3(16, 48), 256, 0, stream>>>(gru_Whh_f, WhhT_f, H3sz, Lsz, Lsz, Lsz, 0);
    transp_kernel<<<dim3(16, 48), 256, 0, stream>>>(gru_Whh_b, WhhT_b, H3sz, Lsz, Lsz, Lsz, 0);
    transp_kernel<<<dim3(5, 48), 256, 0, stream>>>(gru_Wih_f, WihT_f, H3sz, DIN, KPAD, DIN, 0);
    transp_kernel<<<dim3(5, 48), 256, 0, stream>>>(gru_Wih_b, WihT_b, H3sz, DIN, KPAD, DIN, 0);
    transp_kernel<<<dim3(5, 2), 256, 0, stream>>>(W_reduce_txt, WrtT, Rsz, DIN, KPAD, DIN, 0);
    transp_kernel<<<dim3(16, 16), 256, 0, stream>>>(sa_Wv, WvT, Lsz, Lsz, Lsz, Lsz, 0);
    transp_kernel<<<dim3(2, 16), 256, 0, stream>>>(W_txt_fc, WfcT, Lsz, Rsz, Rsz, Rsz + Lsz, Lsz);
    captr_kernel<<<dim3(32, 5), 256, 0, stream>>>(cap_embed, capTr);

    // 2) image-side precompute + generated weights (directly transposed)
    img_kernel<<<64, 256, 0, stream>>>(img_embed, W_reduce_img, b_reduce_img, base, iv);
    genw_gemm<<<dim3(3, 129, 2), 256, 0, stream>>>(gen_Wih, gen_bih, gen_Whh, gen_bhh,
        gen_Wbih, gen_bbih, gen_Wbhh, gen_bbhh, base, WihAllT, WhhAllT, bihAll, bhhAll);

    // 3) gi (both dirs) + cap_reduced
    gemm_tt<<<dim3(16, 24, 2), 256, 0, stream>>>(WihT_f, WihT_b, capTr,
        gru_bih_f, gru_bih_b, giT2_f, giT2_b, H3sz);
    gemm_tt<<<dim3(16, 1, 1), 256, 0, stream>>>(WrtT, WrtT, capTr,
        b_reduce_txt, b_reduce_txt, capT2, capT2, Rsz);

    // 4) recurrences
    for (int s = 0; s < Tsz; s++) {
        const float* hp = (s & 1) ? hA : hB;   // unused at s==0
        float* hc = (s & 1) ? hB : hA;
        if (s == 0) hp = hA;
        step_gemm2<<<512, 256, 0, stream>>>(hfT, hbT, WhhT_f, WhhT_b,
            capT2, WihAllT, WhhAllT, hp, pcap, pgen, s);
        step_gates2<<<640, 256, 0, stream>>>(pcap, pgen, giT2_f, giT2_b, hfT, hbT,
            gru_bhh_f, gru_bhh_b, bihAll, bhhAll, hp, hc, hmaxT, s);
    }
    hstdT_kernel<<<64, 256, 0, stream>>>(hmaxT, hstdT);

    // 5) combine + self-attention (v via K-split TT GEMM, ksplit=2)
    txt_combine<<<dim3(32, 16), 256, 0, stream>>>(hfT, hbT, txt, txtT);
    gemm_bias<<<dim3(2, 32, 2), 256, 0, stream>>>(txt, Lsz, sa_Wq, sa_Wk, Lsz, 0,
        sa_bq, sa_bk, qbuf, kbuf, Bsz * Tsz, Rsz, Lsz);
    gemm_ttp<<<dim3(16, 8, 2), 256, 0, stream>>>(WvT, txtT, vP, Lsz, NC, 512);
    attn_kernel<<<dim3(64, 8), 256, 0, stream>>>(qbuf, kbuf, vP, sa_bv, txt,
        sa_gamma, xattn);

    // 6) pool + image-independent FC part (transposed output)
    pool_kernel<<<dim3(64, 4), 256, 0, stream>>>(xattn, lens, txt_emb);
    basefc_kernel<<<256, 256, 0, stream>>>(txt_emb, W_txt_fc, base_fcT);

    // 7) fc delta (column layout) + sims partial/final
    gemm_ttp<<<dim3(32, 8, 1), 256, 0, stream>>>(WfcT, hstdT, fcT, Lsz, 4096, Rsz);
    sims_part<<<dim3(64, 4), 256, 0, stream>>>(fcT, base_fcT, b_txt_fc, iv, accA, accB);
    sims_final<<<16, 256, 0, stream>>>(accA, accB, (float*)d_out);
}

// Round 11
// 1810.478 us; speedup vs baseline: 1.1744x; 1.0551x over previous
//
#include <hip/hip_runtime.h>
#include <math.h>

// ---------------- problem constants ----------------
#define Lsz   1024
#define Tsz   32
#define Bsz   64
#define DIN   300
#define REG   36
#define Rsz   128
#define R3sz  384
#define H3sz  3072
#define GENROWS 49152   // R3sz * Rsz
#define NC    2048      // caption columns c = t*64 + b
#define KPAD  304       // DIN padded to /16

__device__ __forceinline__ float sigf(float x) { return 1.f / (1.f + __expf(-x)); }

// =====================================================================
// Generic transpose: out[c*R + r] = in[r*lda + woff + c], c < Cin,
// zero-pad c in [Cin, Cpad). grid (ceil(Cpad/64), ceil(R/64)).
// =====================================================================
__global__ __launch_bounds__(256) void transp_kernel(
    const float* __restrict__ in, float* __restrict__ out,
    int R, int Cin, int Cpad, int lda, int woff)
{
    __shared__ float s[64][65];
    int c0 = blockIdx.x * 64, r0 = blockIdx.y * 64;
    int tid = threadIdx.x;
#pragma unroll
    for (int l = 0; l < 16; l++) {
        int e = l * 256 + tid;
        int rr = e >> 6, cc = e & 63;
        int r = r0 + rr, c = c0 + cc;
        s[rr][cc] = (r < R && c < Cin) ? in[(size_t)r * lda + woff + c] : 0.f;
    }
    __syncthreads();
#pragma unroll
    for (int l = 0; l < 16; l++) {
        int e = l * 256 + tid;
        int cc = e >> 6, rr = e & 63;
        int c = c0 + cc, r = r0 + rr;
        if (c < Cpad && r < R) out[(size_t)c * R + r] = s[rr][cc];
    }
}

// =====================================================================
// cap_embed [b][t][d] -> capTr [k][t*64+b], k zero-padded to 304.
// =====================================================================
__global__ __launch_bounds__(256) void captr_kernel(
    const float* __restrict__ cap_embed, float* __restrict__ capTr)
{
    __shared__ float s[64][65];
    int t = blockIdx.x, kc = blockIdx.y;
    int tid = threadIdx.x;
#pragma unroll
    for (int l = 0; l < 16; l++) {
        int e = l * 256 + tid;
        int b = e >> 6, kk = e & 63;
        int k = kc * 64 + kk;
        s[b][kk] = (k < DIN) ? cap_embed[((size_t)b * Tsz + t) * DIN + k] : 0.f;
    }
    __syncthreads();
#pragma unroll
    for (int l = 0; l < 16; l++) {
        int e = l * 256 + tid;
        int kk = e >> 6, b = e & 63;
        int k = kc * 64 + kk;
        if (k < KPAD)
            capTr[(size_t)k * NC + t * 64 + b] = s[b][kk];
    }
}

// =====================================================================
// All-transposed GEMM for gi: C[n][c] = sum_k WT[k][n]*X[k][c] + bias[n].
// WT [KPAD][Ntot], X [KPAD][NC]. Tile 128x128, 8x8 reg tile.
// =====================================================================
__global__ __launch_bounds__(256) void gemm_tt(
    const float* __restrict__ WT1, const float* __restrict__ WT2,
    const float* __restrict__ X,
    const float* __restrict__ b1, const float* __restrict__ b2,
    float* __restrict__ C1, float* __restrict__ C2, int Ntot)
{
    const float* WT = blockIdx.z ? WT2 : WT1;
    const float* bias = blockIdx.z ? b2 : b1;
    float* C = blockIdx.z ? C2 : C1;
    __shared__ float Ws[16][132];
    __shared__ float Xs[16][132];
    int tid = threadIdx.x, tx = tid & 15, ty = tid >> 4;
    int c0 = blockIdx.x * 128, n0 = blockIdx.y * 128;
    float acc[8][8];
#pragma unroll
    for (int i = 0; i < 8; i++)
#pragma unroll
        for (int j = 0; j < 8; j++) acc[i][j] = 0.f;

    for (int k0 = 0; k0 < KPAD; k0 += 16) {
#pragma unroll
        for (int l = 0; l < 2; l++) {
            int e = l * 256 + tid;
            int l16 = e & 15, seg = e >> 4;
            int kk = seg & 15, half = seg >> 4;
            int col = half * 64 + l16 * 4;
            *(float4*)&Ws[kk][col] = *(const float4*)&WT[(size_t)(k0 + kk) * Ntot + n0 + col];
            *(float4*)&Xs[kk][col] = *(const float4*)&X[(size_t)(k0 + kk) * NC + c0 + col];
        }
        __syncthreads();
#pragma unroll
        for (int kk = 0; kk < 16; kk++) {
            float a[8], x[8];
            *(float4*)&a[0] = *(const float4*)&Ws[kk][ty * 8];
            *(float4*)&a[4] = *(const float4*)&Ws[kk][ty * 8 + 4];
            *(float4*)&x[0] = *(const float4*)&Xs[kk][tx * 8];
            *(float4*)&x[4] = *(const float4*)&Xs[kk][tx * 8 + 4];
#pragma unroll
            for (int i = 0; i < 8; i++)
#pragma unroll
                for (int j = 0; j < 8; j++) acc[i][j] = fmaf(a[i], x[j], acc[i][j]);
        }
        __syncthreads();
    }
#pragma unroll
    for (int i = 0; i < 8; i++) {
        int n = n0 + ty * 8 + i;
        float bv = bias[n];
        *(float4*)&C[(size_t)n * NC + c0 + tx * 8] =
            make_float4(acc[i][0] + bv, acc[i][1] + bv, acc[i][2] + bv, acc[i][3] + bv);
        *(float4*)&C[(size_t)n * NC + c0 + tx * 8 + 4] =
            make_float4(acc[i][4] + bv, acc[i][5] + bv, acc[i][6] + bv, acc[i][7] + bv);
    }
}

// =====================================================================
// Parametrized TT GEMM with K-split: z selects k-range, separate partial
// buffer per z. WT [Ktot][Ntot], X [Ktot][ncols].
// =====================================================================
__global__ __launch_bounds__(256) void gemm_ttp(
    const float* __restrict__ WT, const float* __restrict__ X,
    float* __restrict__ C, int Ntot, int ncols, int klen)
{
    int z = blockIdx.z;
    int kbase = z * klen;
    float* Cp = C + (size_t)z * Ntot * ncols;
    __shared__ float Ws[16][132];
    __shared__ float Xs[16][132];
    int tid = threadIdx.x, tx = tid & 15, ty = tid >> 4;
    int c0 = blockIdx.x * 128, n0 = blockIdx.y * 128;
    float acc[8][8];
#pragma unroll
    for (int i = 0; i < 8; i++)
#pragma unroll
        for (int j = 0; j < 8; j++) acc[i][j] = 0.f;

    for (int k0 = 0; k0 < klen; k0 += 16) {
#pragma unroll
        for (int l = 0; l < 2; l++) {
            int e = l * 256 + tid;
            int l16 = e & 15, seg = e >> 4;
            int kk = seg & 15, half = seg >> 4;
            int col = half * 64 + l16 * 4;
            *(float4*)&Ws[kk][col] =
                *(const float4*)&WT[(size_t)(kbase + k0 + kk) * Ntot + n0 + col];
            *(float4*)&Xs[kk][col] =
                *(const float4*)&X[(size_t)(kbase + k0 + kk) * ncols + c0 + col];
        }
        __syncthreads();
#pragma unroll
        for (int kk = 0; kk < 16; kk++) {
            float a[8], x[8];
            *(float4*)&a[0] = *(const float4*)&Ws[kk][ty * 8];
            *(float4*)&a[4] = *(const float4*)&Ws[kk][ty * 8 + 4];
            *(float4*)&x[0] = *(const float4*)&Xs[kk][tx * 8];
            *(float4*)&x[4] = *(const float4*)&Xs[kk][tx * 8 + 4];
#pragma unroll
            for (int i = 0; i < 8; i++)
#pragma unroll
                for (int j = 0; j < 8; j++) acc[i][j] = fmaf(a[i], x[j], acc[i][j]);
        }
        __syncthreads();
    }
#pragma unroll
    for (int i = 0; i < 8; i++) {
        int n = n0 + ty * 8 + i;
        *(float4*)&Cp[(size_t)n * ncols + c0 + tx * 8] =
            make_float4(acc[i][0], acc[i][1], acc[i][2], acc[i][3]);
        *(float4*)&Cp[(size_t)n * ncols + c0 + tx * 8 + 4] =
            make_float4(acc[i][4], acc[i][5], acc[i][6], acc[i][7]);
    }
}

// =====================================================================
// q/k projection as K-split TT GEMM. grid (16 cblk, 2 qk, 8 z).
// WT [1024][128] (per qk), X = txtT [1024][2048]. klen=128.
// Writes partials P[qk][z][128][2048].
// =====================================================================
__global__ __launch_bounds__(256) void gemm_qk(
    const float* __restrict__ WqT, const float* __restrict__ WkT,
    const float* __restrict__ X,
    float* __restrict__ qP, float* __restrict__ kP)
{
    int qk = blockIdx.y, z = blockIdx.z;
    const float* WT = qk ? WkT : WqT;
    float* Cp = (qk ? kP : qP) + (size_t)z * Rsz * NC;
    int kbase = z * 128;
    __shared__ float Ws[16][132];
    __shared__ float Xs[16][132];
    int tid = threadIdx.x, tx = tid & 15, ty = tid >> 4;
    int c0 = blockIdx.x * 128;
    float acc[8][8];
#pragma unroll
    for (int i = 0; i < 8; i++)
#pragma unroll
        for (int j = 0; j < 8; j++) acc[i][j] = 0.f;

    for (int k0 = 0; k0 < 128; k0 += 16) {
#pragma unroll
        for (int l = 0; l < 2; l++) {
            int e = l * 256 + tid;
            int l16 = e & 15, seg = e >> 4;
            int kk = seg & 15, half = seg >> 4;
            int col = half * 64 + l16 * 4;
            *(float4*)&Ws[kk][col] =
                *(const float4*)&WT[(size_t)(kbase + k0 + kk) * Rsz + col];
            *(float4*)&Xs[kk][col] =
                *(const float4*)&X[(size_t)(kbase + k0 + kk) * NC + c0 + col];
        }
        __syncthreads();
#pragma unroll
        for (int kk = 0; kk < 16; kk++) {
            float a[8], x[8];
            *(float4*)&a[0] = *(const float4*)&Ws[kk][ty * 8];
            *(float4*)&a[4] = *(const float4*)&Ws[kk][ty * 8 + 4];
            *(float4*)&x[0] = *(const float4*)&Xs[kk][tx * 8];
            *(float4*)&x[4] = *(const float4*)&Xs[kk][tx * 8 + 4];
#pragma unroll
            for (int i = 0; i < 8; i++)
#pragma unroll
                for (int j = 0; j < 8; j++) acc[i][j] = fmaf(a[i], x[j], acc[i][j]);
        }
        __syncthreads();
    }
    // n covers the full 128 rows (Ntot==128): n = ty*8+i
#pragma unroll
    for (int i = 0; i < 8; i++) {
        int n = ty * 8 + i;
        *(float4*)&Cp[(size_t)n * NC + c0 + tx * 8] =
            make_float4(acc[i][0], acc[i][1], acc[i][2], acc[i][3]);
        *(float4*)&Cp[(size_t)n * NC + c0 + tx * 8 + 4] =
            make_float4(acc[i][4], acc[i][5], acc[i][6], acc[i][7]);
    }
}

// =====================================================================
// qk combine: sum 8 partials + bias, transpose to [b][t][o] layout.
// grid (32 t, 2 qk), 256 thr. Coalesced reads and writes via LDS.
// =====================================================================
__global__ __launch_bounds__(256) void qkc_kernel(
    const float* __restrict__ qP, const float* __restrict__ kP,
    const float* __restrict__ sa_bq, const float* __restrict__ sa_bk,
    float* __restrict__ qbuf, float* __restrict__ kbuf)
{
    __shared__ float s[128][65];
    int t = blockIdx.x, qk = blockIdx.y;
    const float* P = qk ? kP : qP;
    const float* bias = qk ? sa_bk : sa_bq;
    float* dst = qk ? kbuf : qbuf;
    int tid = threadIdx.x;
    for (int e = tid; e < 128 * 64; e += 256) {
        int o = e >> 6, b = e & 63;
        size_t idx = (size_t)o * NC + t * 64 + b;
        float v = 0.f;
#pragma unroll
        for (int z = 0; z < 8; z++)
            v += P[(size_t)z * Rsz * NC + idx];
        s[o][b] = v;
    }
    __syncthreads();
    for (int e = tid; e < 128 * 64; e += 256) {
        int b = e >> 7, o = e & 127;
        dst[((size_t)b * Tsz + t) * Rsz + o] = s[o][b] + bias[o];
    }
}

// =====================================================================
// Generated weights GEMM, emitting the transposed layout [i][k][row].
// grid (3, 129, 2). (See R10 notes.)
// =====================================================================
__global__ __launch_bounds__(256) void genw_gemm(
    const float* __restrict__ gen_Wih, const float* __restrict__ gen_bih,
    const float* __restrict__ gen_Whh, const float* __restrict__ gen_bhh,
    const float* __restrict__ gen_Wbih, const float* __restrict__ gen_bbih,
    const float* __restrict__ gen_Wbhh, const float* __restrict__ gen_bbhh,
    const float* __restrict__ base,
    float* __restrict__ WihAllT, float* __restrict__ WhhAllT,
    float* __restrict__ bihAll, float* __restrict__ bhhAll)
{
    __shared__ float Bs[64][132];
    __shared__ float Ws[16][132];
    __shared__ float bs[128];
    int rtile = blockIdx.x, ky = blockIdx.y, mat = blockIdx.z;
    int r0 = rtile * 128;
    bool normal = (ky < 128);
    int k = normal ? ky : 0;
    const float* W  = normal ? (mat ? gen_Whh : gen_Wih) : (mat ? gen_Wbhh : gen_Wbih);
    const float* bi = normal ? (mat ? gen_bhh : gen_bih) : (mat ? gen_bbhh : gen_bbih);
    float* out      = normal ? (mat ? WhhAllT : WihAllT) : (mat ? bhhAll : bihAll);
    int rowmul = normal ? 128 : 1;
    size_t ostride = normal ? (size_t)GENROWS : (size_t)R3sz;
    size_t obase   = normal ? (size_t)k * R3sz + r0 : (size_t)r0;

    int tid = threadIdx.x, tx = tid & 15, ty = tid >> 4;
#pragma unroll
    for (int l = 0; l < 8; l++) {
        int e = l * 256 + tid;
        int i = e >> 5, p4 = (e & 31) * 4;
        *(float4*)&Bs[i][p4] = *(const float4*)&base[(size_t)i * Rsz + p4];
    }
    if (tid < 128) bs[tid] = bi[(size_t)(r0 + tid) * rowmul + k];

    float acc[4][8];
#pragma unroll
    for (int i = 0; i < 4; i++)
#pragma unroll
        for (int j = 0; j < 8; j++) acc[i][j] = 0.f;

    for (int c = 0; c < 8; c++) {
        int p0 = c * 16;
#pragma unroll
        for (int l = 0; l < 2; l++) {
            int e = l * 256 + tid;
            int rr = e >> 2, pq = (e & 3) * 4;
            size_t rowidx = (size_t)(r0 + rr) * rowmul + k;
            float4 v = *(const float4*)&W[rowidx * Rsz + p0 + pq];
            Ws[pq + 0][rr] = v.x;
            Ws[pq + 1][rr] = v.y;
            Ws[pq + 2][rr] = v.z;
            Ws[pq + 3][rr] = v.w;
        }
        __syncthreads();
#pragma unroll
        for (int kk = 0; kk < 16; kk++) {
            float a[4], b8[8];
#pragma unroll
            for (int ii = 0; ii < 4; ii++) a[ii] = Bs[ty * 4 + ii][p0 + kk];
            *(float4*)&b8[0] = *(const float4*)&Ws[kk][tx * 8];
            *(float4*)&b8[4] = *(const float4*)&Ws[kk][tx * 8 + 4];
#pragma unroll
            for (int ii = 0; ii < 4; ii++)
#pragma unroll
                for (int jj = 0; jj < 8; jj++)
                    acc[ii][jj] = fmaf(a[ii], b8[jj], acc[ii][jj]);
        }
        __syncthreads();
    }
#pragma unroll
    for (int ii = 0; ii < 4; ii++) {
        int i = ty * 4 + ii;
        float* op = out + (size_t)i * ostride + obase + tx * 8;
        *(float4*)&op[0] = make_float4(acc[ii][0] + bs[tx * 8 + 0], acc[ii][1] + bs[tx * 8 + 1],
                                       acc[ii][2] + bs[tx * 8 + 2], acc[ii][3] + bs[tx * 8 + 3]);
        *(float4*)&op[4] = make_float4(acc[ii][4] + bs[tx * 8 + 4], acc[ii][5] + bs[tx * 8 + 5],
                                       acc[ii][6] + bs[tx * 8 + 6], acc[ii][7] + bs[tx * 8 + 7]);
    }
}

// =====================================================================
// Fused image-side precompute. grid 64.
// =====================================================================
__global__ __launch_bounds__(256) void img_kernel(
    const float* __restrict__ img_embed, const float* __restrict__ W_reduce_img,
    const float* __restrict__ b_reduce_img,
    float* __restrict__ base, float* __restrict__ iv)
{
    int i = blockIdx.x;
    int tid = threadIdx.x;
    __shared__ float row[Lsz];
    __shared__ float ps[4];
    for (int c = tid; c < Lsz; c += 256) {
        float s = 0.f;
        for (int r = 0; r < REG; r++) s += img_embed[((size_t)i * REG + r) * Lsz + c];
        row[c] = s * (1.f / (float)REG);
    }
    __syncthreads();
    float ss = 0.f;
    for (int c = tid; c < Lsz; c += 256) { float x = row[c]; ss = fmaf(x, x, ss); }
#pragma unroll
    for (int off = 32; off; off >>= 1) ss += __shfl_down(ss, off, 64);
    int lane = tid & 63, w = tid >> 6;
    if (lane == 0) ps[w] = ss;
    __syncthreads();
    float inv = 1.f / (sqrtf(ps[0] + ps[1] + ps[2] + ps[3]) + 1e-8f);
    for (int c = tid; c < Lsz; c += 256)
        iv[(size_t)i * Lsz + c] = row[c] * inv;
    for (int o = w * 32; o < w * 32 + 32; o++) {
        float a = 0.f;
        const float* wr = W_reduce_img + (size_t)o * Lsz + lane * 16;
        const float* rr = row + lane * 16;
#pragma unroll
        for (int u = 0; u < 16; u++) a = fmaf(wr[u], rr[u], a);
#pragma unroll
        for (int off = 32; off; off >>= 1) a += __shfl_down(a, off, 64);
        if (lane == 0) base[(size_t)i * Rsz + o] = a + b_reduce_img[o];
    }
}

// =====================================================================
// Recurrence phase A, K-chunk 32. grid 512 x 256 thr.
// =====================================================================
__global__ __launch_bounds__(256) void step_gemm2(
    const float* __restrict__ hfT, const float* __restrict__ hbT,
    const float* __restrict__ WhhT_f, const float* __restrict__ WhhT_b,
    const float* __restrict__ capT2,
    const float* __restrict__ WihAllT, const float* __restrict__ WhhAllT,
    const float* __restrict__ hprevT,
    float* __restrict__ pcap, float* __restrict__ pgen, int step)
{
    __shared__ float As[32][196];
    __shared__ float Hs[32][68];
    int tid = threadIdx.x;
    int tx = tid & 15, ty = tid >> 4;
    int bid = blockIdx.x;

    const float* WT; const float* X; float* P;
    int ldn, gstride, jg, kbase;
    size_t xstride;

    if (bid < 256) {
        if (step == 0) return;
        int dir = bid >> 7; int rem = bid & 127;
        jg = rem >> 3; int ks = rem & 7;
        WT = dir ? WhhT_b : WhhT_f;        // [1024][3072]
        kbase = ks * 128;
        const float* hT = dir ? hbT : hfT;
        int t  = dir ? (Tsz - 1 - step) : step;
        int tp = dir ? (t + 1) : (t - 1);
        X = hT + ((size_t)tp * Lsz + ks * 128) * Bsz;
        xstride = Bsz;
        P = pcap + ((((size_t)dir * 8 + ks) * 16 + jg) * 192) * 64;
        ldn = H3sz; gstride = Lsz;
    } else {
        int g = bid - 256;
        int x = g & 7, rest = g >> 3;
        int i = x + 8 * (rest >> 2);
        int sub = rest & 3; int ks = sub >> 1; jg = sub & 1;
        if (ks == 1 && step == 0) return;
        WT = (ks ? WhhAllT : WihAllT) + (size_t)i * GENROWS;   // [128][384]
        kbase = 0;
        if (ks) { X = hprevT + (size_t)i * Rsz * Bsz; xstride = Bsz; }
        else    { X = capT2 + (size_t)step * 64;      xstride = NC;  }
        P = pgen + ((((size_t)i * 2 + ks) * 2 + jg) * 192) * 64;
        ldn = R3sz; gstride = Rsz;
    }

    float acc[12][4];
#pragma unroll
    for (int i = 0; i < 12; i++)
#pragma unroll
        for (int j = 0; j < 4; j++) acc[i][j] = 0.f;

    for (int c = 0; c < 4; c++) {
        int k0 = c * 32;
#pragma unroll
        for (int l = 0; l < 6; l++) {
            int e = l * 256 + tid;
            int l16 = e & 15, seg = e >> 4;        // seg < 96
            int kk = seg & 31, gate = seg >> 5;    // gate in 0..2
            const float* src = WT + (size_t)(kbase + k0 + kk) * ldn
                               + gate * gstride + jg * 64 + l16 * 4;
            *(float4*)&As[kk][gate * 64 + l16 * 4] = *(const float4*)src;
        }
#pragma unroll
        for (int l = 0; l < 2; l++) {
            int e = l * 256 + tid;
            int l16 = e & 15, kk = e >> 4;         // kk < 32
            *(float4*)&Hs[kk][l16 * 4] =
                *(const float4*)&X[(size_t)(k0 + kk) * xstride + l16 * 4];
        }
        __syncthreads();
#pragma unroll
        for (int kk = 0; kk < 32; kk++) {
            float a[12], hb[4];
            *(float4*)&a[0] = *(const float4*)&As[kk][ty * 12];
            *(float4*)&a[4] = *(const float4*)&As[kk][ty * 12 + 4];
            *(float4*)&a[8] = *(const float4*)&As[kk][ty * 12 + 8];
            *(float4*)&hb[0] = *(const float4*)&Hs[kk][tx * 4];
#pragma unroll
            for (int i = 0; i < 12; i++)
#pragma unroll
                for (int j = 0; j < 4; j++) acc[i][j] = fmaf(a[i], hb[j], acc[i][j]);
        }
        __syncthreads();
    }
#pragma unroll
    for (int i = 0; i < 12; i++) {
        int mm = ty * 12 + i;
        *(float4*)&P[(size_t)mm * 64 + tx * 4] =
            make_float4(acc[i][0], acc[i][1], acc[i][2], acc[i][3]);
    }
}

// =====================================================================
// Recurrence phase B: reduce K-slices + gates. grid 640 x 256.
// =====================================================================
__global__ __launch_bounds__(256) void step_gates2(
    const float* __restrict__ pcap, const float* __restrict__ pgen,
    const float* __restrict__ giT2_f, const float* __restrict__ giT2_b,
    float* __restrict__ hfT, float* __restrict__ hbT,
    const float* __restrict__ bhh_f, const float* __restrict__ bhh_b,
    const float* __restrict__ bihAll, const float* __restrict__ bhhAll,
    const float* __restrict__ hprevT, float* __restrict__ hcurT,
    float* __restrict__ hmaxT, int step)
{
    int tid = threadIdx.x;
    int b = tid & 63;
    int bid = blockIdx.x;
    if (bid < 128) {
        int dir = bid >> 6; int rem = bid & 63;
        int jg = rem >> 2, q = rem & 3;
        const float* giT = dir ? giT2_b : giT2_f;
        float* hT        = dir ? hbT   : hfT;
        const float* bhh = dir ? bhh_b : bhh_f;
        int t  = dir ? (Tsz - 1 - step) : step;
        int tp = dir ? (t + 1) : (t - 1);
#pragma unroll
        for (int u = 0; u < 4; u++) {
            int jl = q * 16 + u * 4 + (tid >> 6);
            int j = jg * 64 + jl;
            float gh[3] = {0.f, 0.f, 0.f};
            if (step > 0) {
#pragma unroll
                for (int ks = 0; ks < 8; ks++) {
                    const float* pb = pcap + ((((size_t)dir * 8 + ks) * 16 + jg) * 192) * 64;
#pragma unroll
                    for (int g = 0; g < 3; g++)
                        gh[g] += pb[(size_t)(g * 64 + jl) * 64 + b];
                }
            }
            size_t gc = (size_t)t * 64 + b;
            float gr = giT[(size_t)j * NC + gc];
            float gz = giT[(size_t)(Lsz + j) * NC + gc];
            float gn = giT[(size_t)(2 * Lsz + j) * NC + gc];
            float hp = (step > 0) ? hT[((size_t)tp * Lsz + j) * Bsz + b] : 0.f;
            float r = sigf(gr + gh[0] + bhh[j]);
            float z = sigf(gz + gh[1] + bhh[Lsz + j]);
            float n = tanhf(gn + r * (gh[2] + bhh[2 * Lsz + j]));
            hT[((size_t)t * Lsz + j) * Bsz + b] = (1.f - z) * n + z * hp;
        }
    } else {
        int g2 = bid - 128;
        int i = g2 >> 3; int rest = g2 & 7;
        int jg = rest >> 2, q = rest & 3;
        const float* bih = bihAll + (size_t)i * R3sz;
        const float* bhh = bhhAll + (size_t)i * R3sz;
        const float* p0 = pgen + ((((size_t)i * 2 + 0) * 2 + jg) * 192) * 64;
        const float* p1 = pgen + ((((size_t)i * 2 + 1) * 2 + jg) * 192) * 64;
#pragma unroll
        for (int u = 0; u < 4; u++) {
            int jl = q * 16 + u * 4 + (tid >> 6);
            int j = jg * 64 + jl;
            float sih[3], shh[3];
#pragma unroll
            for (int g = 0; g < 3; g++) {
                sih[g] = p0[(size_t)(g * 64 + jl) * 64 + b];
                shh[g] = (step > 0) ? p1[(size_t)(g * 64 + jl) * 64 + b] : 0.f;
            }
            float r = sigf(sih[0] + bih[j] + shh[0] + bhh[j]);
            float z = sigf(sih[1] + bih[Rsz + j] + shh[1] + bhh[Rsz + j]);
            float n = tanhf(sih[2] + bih[2 * Rsz + j] + r * (shh[2] + bhh[2 * Rsz + j]));
            float hp = (step > 0) ? hprevT[((size_t)i * Rsz + j) * Bsz + b] : 0.f;
            float h = (1.f - z) * n + z * hp;
            size_t idx = ((size_t)i * Rsz + j) * Bsz + b;
            hcurT[idx] = h;
            hmaxT[idx] = (step == 0) ? h : fmaxf(hmaxT[idx], h);
        }
    }
}

// =====================================================================
// txt = (hf+hb)/2 -> row-major txt [b][t][c] AND column txtT [c][t*64+b].
// grid (32, 16).
// =====================================================================
__global__ __launch_bounds__(256) void txt_combine(
    const float* __restrict__ hfT, const float* __restrict__ hbT,
    float* __restrict__ txt, float* __restrict__ txtT)
{
    __shared__ float s[64][65];
    int t = blockIdx.x;
    int c0 = blockIdx.y * 64;
    int tid = threadIdx.x;
#pragma unroll
    for (int l = 0; l < 16; l++) {
        int e = l * 256 + tid;
        int cc = e >> 6, b = e & 63;
        size_t idx = ((size_t)t * Lsz + c0 + cc) * Bsz + b;
        s[cc][b] = 0.5f * (hfT[idx] + hbT[idx]);
    }
    __syncthreads();
#pragma unroll
    for (int l = 0; l < 16; l++) {
        int e = l * 256 + tid;
        int b = e >> 6, cc = e & 63;
        txt[((size_t)b * Tsz + t) * Lsz + c0 + cc] = s[cc][b];
    }
#pragma unroll
    for (int l = 0; l < 16; l++) {
        int e = l * 256 + tid;
        int cc = e >> 6, b = e & 63;
        txtT[(size_t)(c0 + cc) * NC + t * 64 + b] = s[cc][b];
    }
}

// =====================================================================
// Self-attention. v comes as 2 K-split partials vP[z][c][t*64+b];
// summed + bias while staging. grid (64, 8).
// =====================================================================
__global__ __launch_bounds__(256) void attn_kernel(
    const float* __restrict__ q, const float* __restrict__ kmat,
    const float* __restrict__ vP, const float* __restrict__ sa_bv,
    const float* __restrict__ txt,
    const float* __restrict__ gamma_p, float* __restrict__ xattn)
{
    __shared__ float qs[32][129];
    __shared__ float ks[32][129];
    __shared__ float Sc[32][33];
    __shared__ float vs[128][33];
    int b = blockIdx.x;
    int c0 = blockIdx.y * 128;
    int tid = threadIdx.x;
    for (int e = tid; e < Tsz * Rsz; e += 256) {
        qs[e >> 7][e & 127] = q[(size_t)b * Tsz * Rsz + e];
        ks[e >> 7][e & 127] = kmat[(size_t)b * Tsz * Rsz + e];
    }
    for (int e = tid; e < 128 * 32; e += 256) {
        int cc = e >> 5, ss = e & 31;
        size_t base = (size_t)(c0 + cc) * NC + ss * 64 + b;
        float v = sa_bv[c0 + cc];
#pragma unroll
        for (int z = 0; z < 2; z++)
            v += vP[(size_t)z * Lsz * NC + base];
        vs[cc][ss] = v;
    }
    __syncthreads();
    for (int e = tid; e < Tsz * Tsz; e += 256) {
        int t = e >> 5, ss = e & 31;
        float acc = 0.f;
#pragma unroll 4
        for (int o = 0; o < Rsz; o++) acc = fmaf(qs[t][o], ks[ss][o], acc);
        Sc[t][ss] = acc;
    }
    __syncthreads();
    if (tid < 32) {
        int t = tid;
        float mx = -1e30f;
#pragma unroll
        for (int ss = 0; ss < 32; ss++) mx = fmaxf(mx, Sc[t][ss]);
        float sum = 0.f;
        float ex[32];
#pragma unroll
        for (int ss = 0; ss < 32; ss++) { ex[ss] = __expf(Sc[t][ss] - mx); sum += ex[ss]; }
        float inv = 1.f / sum;
#pragma unroll
        for (int ss = 0; ss < 32; ss++) Sc[t][ss] = ex[ss] * inv;
    }
    __syncthreads();
    float gamma = *gamma_p;
    for (int e = tid; e < Tsz * 128; e += 256) {
        int tt = e >> 7, cc = e & 127;
        float acc = 0.f;
#pragma unroll 8
        for (int ss = 0; ss < Tsz; ss++)
            acc = fmaf(Sc[tt][ss], vs[cc][ss], acc);
        size_t oidx = ((size_t)b * Tsz + tt) * Lsz + c0 + cc;
        xattn[oidx] = gamma * acc + txt[oidx];
    }
}

// ---------------- length-masked mean pool, grid (64,4) ----------------
__global__ __launch_bounds__(256) void pool_kernel(
    const float* __restrict__ xattn, const int* __restrict__ lens,
    float* __restrict__ txt_embed)
{
    int b = blockIdx.x;
    int c = blockIdx.y * 256 + threadIdx.x;
    int len = lens[b];
    float s = 0.f;
    for (int t = 0; t < len; t++) s += xattn[((size_t)b * Tsz + t) * Lsz + c];
    txt_embed[(size_t)b * Lsz + c] = s / (float)len;
}

// =====================================================================
// base_fcT[n][b] = dot(txt_emb[b][:], W_txt_fc[n][0:1024]). grid 256.
// =====================================================================
__global__ __launch_bounds__(256) void basefc_kernel(
    const float* __restrict__ temb, const float* __restrict__ W,
    float* __restrict__ outT)
{
    int lane = threadIdx.x & 63, w = threadIdx.x >> 6;
    int n = blockIdx.x * 4 + w;
    const float* wr = W + (size_t)n * (Rsz + Lsz) + lane * 16;
    float wv[16];
#pragma unroll
    for (int u = 0; u < 4; u++) *(float4*)&wv[u * 4] = *(const float4*)&wr[u * 4];
    for (int b = 0; b < Bsz; b++) {
        const float* te = temb + (size_t)b * Lsz + lane * 16;
        float tv[16];
#pragma unroll
        for (int u = 0; u < 4; u++) *(float4*)&tv[u * 4] = *(const float4*)&te[u * 4];
        float a = 0.f;
#pragma unroll
        for (int u = 0; u < 16; u++) a = fmaf(wv[u], tv[u], a);
#pragma unroll
        for (int off = 32; off; off >>= 1) a += __shfl_down(a, off, 64);
        if (lane == 0) outT[(size_t)n * Bsz + b] = a;
    }
}

// ---- hmaxT [i][j][b] -> hstdT [j][i*64+b], coalesced permute. grid 64 ----
__global__ __launch_bounds__(256) void hstdT_kernel(
    const float* __restrict__ hmaxT, float* __restrict__ hstdT)
{
    int i = blockIdx.x, tid = threadIdx.x;
    int b = tid & 63, j0 = tid >> 6;
#pragma unroll
    for (int l = 0; l < 32; l++) {
        int j = l * 4 + j0;
        hstdT[(size_t)j * 4096 + i * 64 + b] = hmaxT[((size_t)i * Rsz + j) * Bsz + b];
    }
}

// =====================================================================
// sims partial reduce: column layouts, fully coalesced. grid (64, 4).
// =====================================================================
__global__ __launch_bounds__(256) void sims_part(
    const float* __restrict__ fcT, const float* __restrict__ base_fcT,
    const float* __restrict__ bfc, const float* __restrict__ iv,
    float* __restrict__ accA, float* __restrict__ accB)
{
    int i = blockIdx.x, cs = blockIdx.y;
    int tid = threadIdx.x;
    int w = tid >> 6, b = tid & 63;
    float s1 = 0.f, s2 = 0.f;
    for (int u = 0; u < 64; u++) {
        int c = cs * 256 + w * 64 + u;
        float f = fcT[(size_t)c * 4096 + i * 64 + b] + base_fcT[(size_t)c * Bsz + b] + bfc[c];
        s1 = fmaf(f, f, s1);
        s2 = fmaf(f, iv[(size_t)i * Lsz + c], s2);
    }
    int m = i * 64 + b;
    atomicAdd(&accA[m], s1);
    atomicAdd(&accB[m], s2);
}

__global__ __launch_bounds__(256) void sims_final(
    const float* __restrict__ accA, const float* __restrict__ accB,
    float* __restrict__ out)
{
    int m = blockIdx.x * 256 + threadIdx.x;
    out[m] = accB[m] / (sqrtf(accA[m]) + 1e-8f);
}

// =====================================================================
extern "C" void kernel_launch(void* const* d_in, const int* in_sizes, int n_in,
                              void* d_out, int out_size, void* d_ws, size_t ws_size,
                              hipStream_t stream)
{
    const float* img_embed    = (const float*)d_in[0];
    const float* cap_embed    = (const float*)d_in[1];
    const int*   lens         = (const int*)d_in[2];
    const float* W_reduce_img = (const float*)d_in[3];
    const float* b_reduce_img = (const float*)d_in[4];
    const float* W_reduce_txt = (const float*)d_in[5];
    const float* b_reduce_txt = (const float*)d_in[6];
    const float* gru_Wih_f    = (const float*)d_in[7];
    const float* gru_Whh_f    = (const float*)d_in[8];
    const float* gru_bih_f    = (const float*)d_in[9];
    const float* gru_bhh_f    = (const float*)d_in[10];
    const float* gru_Wih_b    = (const float*)d_in[11];
    const float* gru_Whh_b    = (const float*)d_in[12];
    const float* gru_bih_b    = (const float*)d_in[13];
    const float* gru_bhh_b    = (const float*)d_in[14];
    const float* sa_Wq        = (const float*)d_in[15];
    const float* sa_bq        = (const float*)d_in[16];
    const float* sa_Wk        = (const float*)d_in[17];
    const float* sa_bk        = (const float*)d_in[18];
    const float* sa_Wv        = (const float*)d_in[19];
    const float* sa_bv        = (const float*)d_in[20];
    const float* sa_gamma     = (const float*)d_in[21];
    const float* gen_Wih      = (const float*)d_in[22];
    const float* gen_bih      = (const float*)d_in[23];
    const float* gen_Whh      = (const float*)d_in[24];
    const float* gen_bhh      = (const float*)d_in[25];
    const float* gen_Wbih     = (const float*)d_in[26];
    const float* gen_bbih     = (const float*)d_in[27];
    const float* gen_Wbhh     = (const float*)d_in[28];
    const float* gen_bbhh     = (const float*)d_in[29];
    const float* W_txt_fc     = (const float*)d_in[30];
    const float* b_txt_fc     = (const float*)d_in[31];

    float* ws = (float*)d_ws;
    size_t off = 0;
    auto alloc = [&](size_t n) { float* p = ws + off; off += n; return p; };
    float* giT2_f   = alloc((size_t)H3sz * NC);
    float* giT2_b   = alloc((size_t)H3sz * NC);
    float* hfT      = alloc((size_t)Tsz * Lsz * Bsz);
    float* hbT      = alloc((size_t)Tsz * Lsz * Bsz);
    float* capTr    = alloc((size_t)KPAD * NC);
    float* capT2    = alloc((size_t)Rsz * NC);
    float* txt      = alloc((size_t)Bsz * Tsz * Lsz);
    float* txtT     = alloc((size_t)Lsz * NC);
    float* qbuf     = alloc((size_t)Bsz * Tsz * Rsz);
    float* kbuf     = alloc((size_t)Bsz * Tsz * Rsz);
    float* qP       = alloc((size_t)8 * Rsz * NC);       // 8 K-split partials
    float* kP       = alloc((size_t)8 * Rsz * NC);
    float* vP       = alloc((size_t)2 * Lsz * NC);       // 2 K-split partials
    float* xattn    = alloc((size_t)Bsz * Tsz * Lsz);
    float* txt_emb  = alloc((size_t)Bsz * Lsz);
    float* base     = alloc((size_t)Bsz * Rsz);
    float* iv       = alloc((size_t)Bsz * Lsz);
    float* WihAllT  = alloc((size_t)Bsz * GENROWS);      // [i][128][384]
    float* WhhAllT  = alloc((size_t)Bsz * GENROWS);
    float* WhhT_f   = alloc((size_t)Lsz * H3sz);
    float* WhhT_b   = alloc((size_t)Lsz * H3sz);
    float* WihT_f   = alloc((size_t)KPAD * H3sz);
    float* WihT_b   = alloc((size_t)KPAD * H3sz);
    float* WrtT     = alloc((size_t)KPAD * Rsz);
    float* WvT      = alloc((size_t)Lsz * Lsz);
    float* WqT      = alloc((size_t)Lsz * Rsz);
    float* WkT      = alloc((size_t)Lsz * Rsz);
    float* WfcT     = alloc((size_t)Rsz * Lsz);
    float* bihAll   = alloc((size_t)Bsz * R3sz);
    float* bhhAll   = alloc((size_t)Bsz * R3sz);
    float* hA       = alloc((size_t)Bsz * Rsz * Bsz);
    float* hB       = alloc((size_t)Bsz * Rsz * Bsz);
    float* hmaxT    = alloc((size_t)Bsz * Rsz * Bsz);
    float* hstdT    = alloc((size_t)Rsz * Bsz * Bsz);
    float* base_fcT = alloc((size_t)Lsz * Bsz);
    float* fcT      = alloc((size_t)Lsz * Bsz * Bsz);    // [1024][4096]
    float* accA     = alloc(4096);
    float* accB     = alloc(4096);
    // Aliases (disjoint lifetimes):
    float* pcap = fcT;        // 3.15M floats in fcT (4.19M); fcT written later
    float* pgen = vP;         // 3.15M floats in vP (4.19M); vP written later

    // 0) zero the sims accumulators
    hipMemsetAsync(accA, 0, 2 * 4096 * sizeof(float), stream);

    // 1) one-time transposes
    transp_kernel<<<dim3(16, 48), 256, 0, stream>>>(gru_Whh_f, WhhT_f, H3sz, Lsz, Lsz, Lsz, 0);
    transp_kernel<<<dim3(16, 48), 256, 0, stream>>>(gru_Whh_b, WhhT_b, H3sz, Lsz, Lsz, Lsz, 0);
    transp_kernel<<<dim3(5, 48), 256, 0, stream>>>(gru_Wih_f, WihT_f, H3sz, DIN, KPAD, DIN, 0);
    transp_kernel<<<dim3(5, 48), 256, 0, stream>>>(gru_Wih_b, WihT_b, H3sz, DIN, KPAD, DIN, 0);
    transp_kernel<<<dim3(5, 2), 256, 0, stream>>>(W_reduce_txt, WrtT, Rsz, DIN, KPAD, DIN, 0);
    transp_kernel<<<dim3(16, 16), 256, 0, stream>>>(sa_Wv, WvT, Lsz, Lsz, Lsz, Lsz, 0);
    transp_kernel<<<dim3(16, 2), 256, 0, stream>>>(sa_Wq, WqT, Rsz, Lsz, Lsz, Lsz, 0);
    transp_kernel<<<dim3(16, 2), 256, 0, stream>>>(sa_Wk, WkT, Rsz, Lsz, Lsz, Lsz, 0);
    transp_kernel<<<dim3(2, 16), 256, 0, stream>>>(W_txt_fc, WfcT, Lsz, Rsz, Rsz, Rsz + Lsz, Lsz);
    captr_kernel<<<dim3(32, 5), 256, 0, stream>>>(cap_embed, capTr);

    // 2) image-side precompute + generated weights (directly transposed)
    img_kernel<<<64, 256, 0, stream>>>(img_embed, W_reduce_img, b_reduce_img, base, iv);
    genw_gemm<<<dim3(3, 129, 2), 256, 0, stream>>>(gen_Wih, gen_bih, gen_Whh, gen_bhh,
        gen_Wbih, gen_bbih, gen_Wbhh, gen_bbhh, base, WihAllT, WhhAllT, bihAll, bhhAll);

    // 3) gi (both dirs) + cap_reduced
    gemm_tt<<<dim3(16, 24, 2), 256, 0, stream>>>(WihT_f, WihT_b, capTr,
        gru_bih_f, gru_bih_b, giT2_f, giT2_b, H3sz);
    gemm_tt<<<dim3(16, 1, 1), 256, 0, stream>>>(WrtT, WrtT, capTr,
        b_reduce_txt, b_reduce_txt, capT2, capT2, Rsz);

    // 4) recurrences
    for (int s = 0; s < Tsz; s++) {
        const float* hp = (s & 1) ? hA : hB;   // unused at s==0
        float* hc = (s & 1) ? hB : hA;
        if (s == 0) hp = hA;
        step_gemm2<<<512, 256, 0, stream>>>(hfT, hbT, WhhT_f, WhhT_b,
            capT2, WihAllT, WhhAllT, hp, pcap, pgen, s);
        step_gates2<<<640, 256, 0, stream>>>(pcap, pgen, giT2_f, giT2_b, hfT, hbT,
            gru_bhh_f, gru_bhh_b, bihAll, bhhAll, hp, hc, hmaxT, s);
    }
    hstdT_kernel<<<64, 256, 0, stream>>>(hmaxT, hstdT);

    // 5) combine + self-attention (q/k/v all via K-split TT GEMMs)
    txt_combine<<<dim3(32, 16), 256, 0, stream>>>(hfT, hbT, txt, txtT);
    gemm_qk<<<dim3(16, 2, 8), 256, 0, stream>>>(WqT, WkT, txtT, qP, kP);
    gemm_ttp<<<dim3(16, 8, 2), 256, 0, stream>>>(WvT, txtT, vP, Lsz, NC, 512);
    qkc_kernel<<<dim3(32, 2), 256, 0, stream>>>(qP, kP, sa_bq, sa_bk, qbuf, kbuf);
    attn_kernel<<<dim3(64, 8), 256, 0, stream>>>(qbuf, kbuf, vP, sa_bv, txt,
        sa_gamma, xattn);

    // 6) pool + image-independent FC part (transposed output)
    pool_kernel<<<dim3(64, 4), 256, 0, stream>>>(xattn, lens, txt_emb);
    basefc_kernel<<<256, 256, 0, stream>>>(txt_emb, W_txt_fc, base_fcT);

    // 7) fc delta (column layout) + sims partial/final
    gemm_ttp<<<dim3(32, 8, 1), 256, 0, stream>>>(WfcT, hstdT, fcT, Lsz, 4096, Rsz);
    sims_part<<<dim3(64, 4), 256, 0, stream>>>(fcT, base_fcT, b_txt_fc, iv, accA, accB);
    sims_final<<<16, 256, 0, stream>>>(accA, accB, (float*)d_out);
}

// Round 12
// 1775.299 us; speedup vs baseline: 1.1976x; 1.0198x over previous
//
#include <hip/hip_runtime.h>
#include <math.h>

// ---------------- problem constants ----------------
#define Lsz   1024
#define Tsz   32
#define Bsz   64
#define DIN   300
#define REG   36
#define Rsz   128
#define R3sz  384
#define H3sz  3072
#define GENROWS 49152   // R3sz * Rsz
#define NC    2048      // caption columns c = t*64 + b
#define KPAD  304       // DIN padded to /16

__device__ __forceinline__ float sigf(float x) { return 1.f / (1.f + __expf(-x)); }

// =====================================================================
// Generic transpose: out[c*R + r] = in[r*lda + woff + c], c < Cin,
// zero-pad c in [Cin, Cpad). grid (ceil(Cpad/64), ceil(R/64)).
// =====================================================================
__global__ __launch_bounds__(256) void transp_kernel(
    const float* __restrict__ in, float* __restrict__ out,
    int R, int Cin, int Cpad, int lda, int woff)
{
    __shared__ float s[64][65];
    int c0 = blockIdx.x * 64, r0 = blockIdx.y * 64;
    int tid = threadIdx.x;
#pragma unroll
    for (int l = 0; l < 16; l++) {
        int e = l * 256 + tid;
        int rr = e >> 6, cc = e & 63;
        int r = r0 + rr, c = c0 + cc;
        s[rr][cc] = (r < R && c < Cin) ? in[(size_t)r * lda + woff + c] : 0.f;
    }
    __syncthreads();
#pragma unroll
    for (int l = 0; l < 16; l++) {
        int e = l * 256 + tid;
        int cc = e >> 6, rr = e & 63;
        int c = c0 + cc, r = r0 + rr;
        if (c < Cpad && r < R) out[(size_t)c * R + r] = s[rr][cc];
    }
}

// =====================================================================
// cap_embed [b][t][d] -> capTr [k][t*64+b], k zero-padded to 304.
// =====================================================================
__global__ __launch_bounds__(256) void captr_kernel(
    const float* __restrict__ cap_embed, float* __restrict__ capTr)
{
    __shared__ float s[64][65];
    int t = blockIdx.x, kc = blockIdx.y;
    int tid = threadIdx.x;
#pragma unroll
    for (int l = 0; l < 16; l++) {
        int e = l * 256 + tid;
        int b = e >> 6, kk = e & 63;
        int k = kc * 64 + kk;
        s[b][kk] = (k < DIN) ? cap_embed[((size_t)b * Tsz + t) * DIN + k] : 0.f;
    }
    __syncthreads();
#pragma unroll
    for (int l = 0; l < 16; l++) {
        int e = l * 256 + tid;
        int kk = e >> 6, b = e & 63;
        int k = kc * 64 + kk;
        if (k < KPAD)
            capTr[(size_t)k * NC + t * 64 + b] = s[b][kk];
    }
}

// =====================================================================
// All-transposed GEMM for gi: C[n][c] = sum_k WT[k][n]*X[k][c] + bias[n].
// WT [KPAD][Ntot], X [KPAD][NC]. Tile 128x128, 8x8 reg tile.
// Thread cols: {tx*4..+3} and {64+tx*4..+3}  (stride-4 LDS reads, 2-way
// bank aliasing = free; the old tx*8 pattern was a 4-way conflict).
// =====================================================================
__global__ __launch_bounds__(256) void gemm_tt(
    const float* __restrict__ WT1, const float* __restrict__ WT2,
    const float* __restrict__ X,
    const float* __restrict__ b1, const float* __restrict__ b2,
    float* __restrict__ C1, float* __restrict__ C2, int Ntot)
{
    const float* WT = blockIdx.z ? WT2 : WT1;
    const float* bias = blockIdx.z ? b2 : b1;
    float* C = blockIdx.z ? C2 : C1;
    __shared__ float Ws[16][132];
    __shared__ float Xs[16][132];
    int tid = threadIdx.x, tx = tid & 15, ty = tid >> 4;
    int c0 = blockIdx.x * 128, n0 = blockIdx.y * 128;
    float acc[8][8];
#pragma unroll
    for (int i = 0; i < 8; i++)
#pragma unroll
        for (int j = 0; j < 8; j++) acc[i][j] = 0.f;

    for (int k0 = 0; k0 < KPAD; k0 += 16) {
#pragma unroll
        for (int l = 0; l < 2; l++) {
            int e = l * 256 + tid;
            int l16 = e & 15, seg = e >> 4;
            int kk = seg & 15, half = seg >> 4;
            int col = half * 64 + l16 * 4;
            *(float4*)&Ws[kk][col] = *(const float4*)&WT[(size_t)(k0 + kk) * Ntot + n0 + col];
            *(float4*)&Xs[kk][col] = *(const float4*)&X[(size_t)(k0 + kk) * NC + c0 + col];
        }
        __syncthreads();
#pragma unroll
        for (int kk = 0; kk < 16; kk++) {
            float a[8], x[8];
            *(float4*)&a[0] = *(const float4*)&Ws[kk][ty * 8];
            *(float4*)&a[4] = *(const float4*)&Ws[kk][ty * 8 + 4];
            *(float4*)&x[0] = *(const float4*)&Xs[kk][tx * 4];
            *(float4*)&x[4] = *(const float4*)&Xs[kk][64 + tx * 4];
#pragma unroll
            for (int i = 0; i < 8; i++)
#pragma unroll
                for (int j = 0; j < 8; j++) acc[i][j] = fmaf(a[i], x[j], acc[i][j]);
        }
        __syncthreads();
    }
#pragma unroll
    for (int i = 0; i < 8; i++) {
        int n = n0 + ty * 8 + i;
        float bv = bias[n];
        *(float4*)&C[(size_t)n * NC + c0 + tx * 4] =
            make_float4(acc[i][0] + bv, acc[i][1] + bv, acc[i][2] + bv, acc[i][3] + bv);
        *(float4*)&C[(size_t)n * NC + c0 + 64 + tx * 4] =
            make_float4(acc[i][4] + bv, acc[i][5] + bv, acc[i][6] + bv, acc[i][7] + bv);
    }
}

// =====================================================================
// Parametrized TT GEMM with K-split: z selects k-range, separate partial
// buffer per z. WT [Ktot][Ntot], X [Ktot][ncols]. Strided-f4 cols.
// =====================================================================
__global__ __launch_bounds__(256) void gemm_ttp(
    const float* __restrict__ WT, const float* __restrict__ X,
    float* __restrict__ C, int Ntot, int ncols, int klen)
{
    int z = blockIdx.z;
    int kbase = z * klen;
    float* Cp = C + (size_t)z * Ntot * ncols;
    __shared__ float Ws[16][132];
    __shared__ float Xs[16][132];
    int tid = threadIdx.x, tx = tid & 15, ty = tid >> 4;
    int c0 = blockIdx.x * 128, n0 = blockIdx.y * 128;
    float acc[8][8];
#pragma unroll
    for (int i = 0; i < 8; i++)
#pragma unroll
        for (int j = 0; j < 8; j++) acc[i][j] = 0.f;

    for (int k0 = 0; k0 < klen; k0 += 16) {
#pragma unroll
        for (int l = 0; l < 2; l++) {
            int e = l * 256 + tid;
            int l16 = e & 15, seg = e >> 4;
            int kk = seg & 15, half = seg >> 4;
            int col = half * 64 + l16 * 4;
            *(float4*)&Ws[kk][col] =
                *(const float4*)&WT[(size_t)(kbase + k0 + kk) * Ntot + n0 + col];
            *(float4*)&Xs[kk][col] =
                *(const float4*)&X[(size_t)(kbase + k0 + kk) * ncols + c0 + col];
        }
        __syncthreads();
#pragma unroll
        for (int kk = 0; kk < 16; kk++) {
            float a[8], x[8];
            *(float4*)&a[0] = *(const float4*)&Ws[kk][ty * 8];
            *(float4*)&a[4] = *(const float4*)&Ws[kk][ty * 8 + 4];
            *(float4*)&x[0] = *(const float4*)&Xs[kk][tx * 4];
            *(float4*)&x[4] = *(const float4*)&Xs[kk][64 + tx * 4];
#pragma unroll
            for (int i = 0; i < 8; i++)
#pragma unroll
                for (int j = 0; j < 8; j++) acc[i][j] = fmaf(a[i], x[j], acc[i][j]);
        }
        __syncthreads();
    }
#pragma unroll
    for (int i = 0; i < 8; i++) {
        int n = n0 + ty * 8 + i;
        *(float4*)&Cp[(size_t)n * ncols + c0 + tx * 4] =
            make_float4(acc[i][0], acc[i][1], acc[i][2], acc[i][3]);
        *(float4*)&Cp[(size_t)n * ncols + c0 + 64 + tx * 4] =
            make_float4(acc[i][4], acc[i][5], acc[i][6], acc[i][7]);
    }
}

// =====================================================================
// q/k projection as K-split TT GEMM. grid (16 cblk, 2 qk, 8 z).
// Strided-f4 cols (conflict-free LDS).
// =====================================================================
__global__ __launch_bounds__(256) void gemm_qk(
    const float* __restrict__ WqT, const float* __restrict__ WkT,
    const float* __restrict__ X,
    float* __restrict__ qP, float* __restrict__ kP)
{
    int qk = blockIdx.y, z = blockIdx.z;
    const float* WT = qk ? WkT : WqT;
    float* Cp = (qk ? kP : qP) + (size_t)z * Rsz * NC;
    int kbase = z * 128;
    __shared__ float Ws[16][132];
    __shared__ float Xs[16][132];
    int tid = threadIdx.x, tx = tid & 15, ty = tid >> 4;
    int c0 = blockIdx.x * 128;
    float acc[8][8];
#pragma unroll
    for (int i = 0; i < 8; i++)
#pragma unroll
        for (int j = 0; j < 8; j++) acc[i][j] = 0.f;

    for (int k0 = 0; k0 < 128; k0 += 16) {
#pragma unroll
        for (int l = 0; l < 2; l++) {
            int e = l * 256 + tid;
            int l16 = e & 15, seg = e >> 4;
            int kk = seg & 15, half = seg >> 4;
            int col = half * 64 + l16 * 4;
            if (half == 0)
                *(float4*)&Ws[kk][col] =
                    *(const float4*)&WT[(size_t)(kbase + k0 + kk) * Rsz + col];
            else
                *(float4*)&Ws[kk][col] =
                    *(const float4*)&WT[(size_t)(kbase + k0 + kk) * Rsz + col - 64 + 64];
            *(float4*)&Xs[kk][col] =
                *(const float4*)&X[(size_t)(kbase + k0 + kk) * NC + c0 + col];
        }
        __syncthreads();
#pragma unroll
        for (int kk = 0; kk < 16; kk++) {
            float a[8], x[8];
            *(float4*)&a[0] = *(const float4*)&Ws[kk][ty * 8];
            *(float4*)&a[4] = *(const float4*)&Ws[kk][ty * 8 + 4];
            *(float4*)&x[0] = *(const float4*)&Xs[kk][tx * 4];
            *(float4*)&x[4] = *(const float4*)&Xs[kk][64 + tx * 4];
#pragma unroll
            for (int i = 0; i < 8; i++)
#pragma unroll
                for (int j = 0; j < 8; j++) acc[i][j] = fmaf(a[i], x[j], acc[i][j]);
        }
        __syncthreads();
    }
#pragma unroll
    for (int i = 0; i < 8; i++) {
        int n = ty * 8 + i;
        *(float4*)&Cp[(size_t)n * NC + c0 + tx * 4] =
            make_float4(acc[i][0], acc[i][1], acc[i][2], acc[i][3]);
        *(float4*)&Cp[(size_t)n * NC + c0 + 64 + tx * 4] =
            make_float4(acc[i][4], acc[i][5], acc[i][6], acc[i][7]);
    }
}

// =====================================================================
// qk combine: sum 8 partials + bias, transpose to [b][t][o] layout.
// grid (32 t, 2 qk), 256 thr.
// =====================================================================
__global__ __launch_bounds__(256) void qkc_kernel(
    const float* __restrict__ qP, const float* __restrict__ kP,
    const float* __restrict__ sa_bq, const float* __restrict__ sa_bk,
    float* __restrict__ qbuf, float* __restrict__ kbuf)
{
    __shared__ float s[128][65];
    int t = blockIdx.x, qk = blockIdx.y;
    const float* P = qk ? kP : qP;
    const float* bias = qk ? sa_bk : sa_bq;
    float* dst = qk ? kbuf : qbuf;
    int tid = threadIdx.x;
    for (int e = tid; e < 128 * 64; e += 256) {
        int o = e >> 6, b = e & 63;
        size_t idx = (size_t)o * NC + t * 64 + b;
        float v = 0.f;
#pragma unroll
        for (int z = 0; z < 8; z++)
            v += P[(size_t)z * Rsz * NC + idx];
        s[o][b] = v;
    }
    __syncthreads();
    for (int e = tid; e < 128 * 64; e += 256) {
        int b = e >> 7, o = e & 127;
        dst[((size_t)b * Tsz + t) * Rsz + o] = s[o][b] + bias[o];
    }
}

// =====================================================================
// Generated weights GEMM, emitting the transposed layout [i][k][row].
// grid (3, 129, 2). Strided-f4 row groups (conflict-free LDS).
// =====================================================================
__global__ __launch_bounds__(256) void genw_gemm(
    const float* __restrict__ gen_Wih, const float* __restrict__ gen_bih,
    const float* __restrict__ gen_Whh, const float* __restrict__ gen_bhh,
    const float* __restrict__ gen_Wbih, const float* __restrict__ gen_bbih,
    const float* __restrict__ gen_Wbhh, const float* __restrict__ gen_bbhh,
    const float* __restrict__ base,
    float* __restrict__ WihAllT, float* __restrict__ WhhAllT,
    float* __restrict__ bihAll, float* __restrict__ bhhAll)
{
    __shared__ float Bs[64][132];
    __shared__ float Ws[16][132];
    __shared__ float bs[128];
    int rtile = blockIdx.x, ky = blockIdx.y, mat = blockIdx.z;
    int r0 = rtile * 128;
    bool normal = (ky < 128);
    int k = normal ? ky : 0;
    const float* W  = normal ? (mat ? gen_Whh : gen_Wih) : (mat ? gen_Wbhh : gen_Wbih);
    const float* bi = normal ? (mat ? gen_bhh : gen_bih) : (mat ? gen_bbhh : gen_bbih);
    float* out      = normal ? (mat ? WhhAllT : WihAllT) : (mat ? bhhAll : bihAll);
    int rowmul = normal ? 128 : 1;
    size_t ostride = normal ? (size_t)GENROWS : (size_t)R3sz;
    size_t obase   = normal ? (size_t)k * R3sz + r0 : (size_t)r0;

    int tid = threadIdx.x, tx = tid & 15, ty = tid >> 4;
#pragma unroll
    for (int l = 0; l < 8; l++) {
        int e = l * 256 + tid;
        int i = e >> 5, p4 = (e & 31) * 4;
        *(float4*)&Bs[i][p4] = *(const float4*)&base[(size_t)i * Rsz + p4];
    }
    if (tid < 128) bs[tid] = bi[(size_t)(r0 + tid) * rowmul + k];

    float acc[4][8];
#pragma unroll
    for (int i = 0; i < 4; i++)
#pragma unroll
        for (int j = 0; j < 8; j++) acc[i][j] = 0.f;

    for (int c = 0; c < 8; c++) {
        int p0 = c * 16;
#pragma unroll
        for (int l = 0; l < 2; l++) {
            int e = l * 256 + tid;
            int rr = e >> 2, pq = (e & 3) * 4;
            size_t rowidx = (size_t)(r0 + rr) * rowmul + k;
            float4 v = *(const float4*)&W[rowidx * Rsz + p0 + pq];
            Ws[pq + 0][rr] = v.x;
            Ws[pq + 1][rr] = v.y;
            Ws[pq + 2][rr] = v.z;
            Ws[pq + 3][rr] = v.w;
        }
        __syncthreads();
#pragma unroll
        for (int kk = 0; kk < 16; kk++) {
            float a[4], b8[8];
#pragma unroll
            for (int ii = 0; ii < 4; ii++) a[ii] = Bs[ty * 4 + ii][p0 + kk];
            *(float4*)&b8[0] = *(const float4*)&Ws[kk][tx * 4];
            *(float4*)&b8[4] = *(const float4*)&Ws[kk][64 + tx * 4];
#pragma unroll
            for (int ii = 0; ii < 4; ii++)
#pragma unroll
                for (int jj = 0; jj < 8; jj++)
                    acc[ii][jj] = fmaf(a[ii], b8[jj], acc[ii][jj]);
        }
        __syncthreads();
    }
#pragma unroll
    for (int ii = 0; ii < 4; ii++) {
        int i = ty * 4 + ii;
        float* op = out + (size_t)i * ostride + obase;
        *(float4*)&op[tx * 4] =
            make_float4(acc[ii][0] + bs[tx * 4 + 0], acc[ii][1] + bs[tx * 4 + 1],
                        acc[ii][2] + bs[tx * 4 + 2], acc[ii][3] + bs[tx * 4 + 3]);
        *(float4*)&op[64 + tx * 4] =
            make_float4(acc[ii][4] + bs[64 + tx * 4 + 0], acc[ii][5] + bs[64 + tx * 4 + 1],
                        acc[ii][6] + bs[64 + tx * 4 + 2], acc[ii][7] + bs[64 + tx * 4 + 3]);
    }
}

// =====================================================================
// Fused image-side precompute. grid 64.
// =====================================================================
__global__ __launch_bounds__(256) void img_kernel(
    const float* __restrict__ img_embed, const float* __restrict__ W_reduce_img,
    const float* __restrict__ b_reduce_img,
    float* __restrict__ base, float* __restrict__ iv)
{
    int i = blockIdx.x;
    int tid = threadIdx.x;
    __shared__ float row[Lsz];
    __shared__ float ps[4];
    for (int c = tid; c < Lsz; c += 256) {
        float s = 0.f;
        for (int r = 0; r < REG; r++) s += img_embed[((size_t)i * REG + r) * Lsz + c];
        row[c] = s * (1.f / (float)REG);
    }
    __syncthreads();
    float ss = 0.f;
    for (int c = tid; c < Lsz; c += 256) { float x = row[c]; ss = fmaf(x, x, ss); }
#pragma unroll
    for (int off = 32; off; off >>= 1) ss += __shfl_down(ss, off, 64);
    int lane = tid & 63, w = tid >> 6;
    if (lane == 0) ps[w] = ss;
    __syncthreads();
    float inv = 1.f / (sqrtf(ps[0] + ps[1] + ps[2] + ps[3]) + 1e-8f);
    for (int c = tid; c < Lsz; c += 256)
        iv[(size_t)i * Lsz + c] = row[c] * inv;
    for (int o = w * 32; o < w * 32 + 32; o++) {
        float a = 0.f;
        const float* wr = W_reduce_img + (size_t)o * Lsz + lane * 16;
        const float* rr = row + lane * 16;
#pragma unroll
        for (int u = 0; u < 16; u++) a = fmaf(wr[u], rr[u], a);
#pragma unroll
        for (int off = 32; off; off >>= 1) a += __shfl_down(a, off, 64);
        if (lane == 0) base[(size_t)i * Rsz + o] = a + b_reduce_img[o];
    }
}

// =====================================================================
// Recurrence phase A, K-chunk 32. grid 512 x 256 thr.
// =====================================================================
__global__ __launch_bounds__(256) void step_gemm2(
    const float* __restrict__ hfT, const float* __restrict__ hbT,
    const float* __restrict__ WhhT_f, const float* __restrict__ WhhT_b,
    const float* __restrict__ capT2,
    const float* __restrict__ WihAllT, const float* __restrict__ WhhAllT,
    const float* __restrict__ hprevT,
    float* __restrict__ pcap, float* __restrict__ pgen, int step)
{
    __shared__ float As[32][196];
    __shared__ float Hs[32][68];
    int tid = threadIdx.x;
    int tx = tid & 15, ty = tid >> 4;
    int bid = blockIdx.x;

    const float* WT; const float* X; float* P;
    int ldn, gstride, jg, kbase;
    size_t xstride;

    if (bid < 256) {
        if (step == 0) return;
        int dir = bid >> 7; int rem = bid & 127;
        jg = rem >> 3; int ks = rem & 7;
        WT = dir ? WhhT_b : WhhT_f;        // [1024][3072]
        kbase = ks * 128;
        const float* hT = dir ? hbT : hfT;
        int t  = dir ? (Tsz - 1 - step) : step;
        int tp = dir ? (t + 1) : (t - 1);
        X = hT + ((size_t)tp * Lsz + ks * 128) * Bsz;
        xstride = Bsz;
        P = pcap + ((((size_t)dir * 8 + ks) * 16 + jg) * 192) * 64;
        ldn = H3sz; gstride = Lsz;
    } else {
        int g = bid - 256;
        int x = g & 7, rest = g >> 3;
        int i = x + 8 * (rest >> 2);
        int sub = rest & 3; int ks = sub >> 1; jg = sub & 1;
        if (ks == 1 && step == 0) return;
        WT = (ks ? WhhAllT : WihAllT) + (size_t)i * GENROWS;   // [128][384]
        kbase = 0;
        if (ks) { X = hprevT + (size_t)i * Rsz * Bsz; xstride = Bsz; }
        else    { X = capT2 + (size_t)step * 64;      xstride = NC;  }
        P = pgen + ((((size_t)i * 2 + ks) * 2 + jg) * 192) * 64;
        ldn = R3sz; gstride = Rsz;
    }

    float acc[12][4];
#pragma unroll
    for (int i = 0; i < 12; i++)
#pragma unroll
        for (int j = 0; j < 4; j++) acc[i][j] = 0.f;

    for (int c = 0; c < 4; c++) {
        int k0 = c * 32;
#pragma unroll
        for (int l = 0; l < 6; l++) {
            int e = l * 256 + tid;
            int l16 = e & 15, seg = e >> 4;        // seg < 96
            int kk = seg & 31, gate = seg >> 5;    // gate in 0..2
            const float* src = WT + (size_t)(kbase + k0 + kk) * ldn
                               + gate * gstride + jg * 64 + l16 * 4;
            *(float4*)&As[kk][gate * 64 + l16 * 4] = *(const float4*)src;
        }
#pragma unroll
        for (int l = 0; l < 2; l++) {
            int e = l * 256 + tid;
            int l16 = e & 15, kk = e >> 4;         // kk < 32
            *(float4*)&Hs[kk][l16 * 4] =
                *(const float4*)&X[(size_t)(k0 + kk) * xstride + l16 * 4];
        }
        __syncthreads();
#pragma unroll
        for (int kk = 0; kk < 32; kk++) {
            float a[12], hb[4];
            *(float4*)&a[0] = *(const float4*)&As[kk][ty * 12];
            *(float4*)&a[4] = *(const float4*)&As[kk][ty * 12 + 4];
            *(float4*)&a[8] = *(const float4*)&As[kk][ty * 12 + 8];
            *(float4*)&hb[0] = *(const float4*)&Hs[kk][tx * 4];
#pragma unroll
            for (int i = 0; i < 12; i++)
#pragma unroll
                for (int j = 0; j < 4; j++) acc[i][j] = fmaf(a[i], hb[j], acc[i][j]);
        }
        __syncthreads();
    }
#pragma unroll
    for (int i = 0; i < 12; i++) {
        int mm = ty * 12 + i;
        *(float4*)&P[(size_t)mm * 64 + tx * 4] =
            make_float4(acc[i][0], acc[i][1], acc[i][2], acc[i][3]);
    }
}

// =====================================================================
// Recurrence phase B: reduce K-slices + gates. grid 640 x 256.
// =====================================================================
__global__ __launch_bounds__(256) void step_gates2(
    const float* __restrict__ pcap, const float* __restrict__ pgen,
    const float* __restrict__ giT2_f, const float* __restrict__ giT2_b,
    float* __restrict__ hfT, float* __restrict__ hbT,
    const float* __restrict__ bhh_f, const float* __restrict__ bhh_b,
    const float* __restrict__ bihAll, const float* __restrict__ bhhAll,
    const float* __restrict__ hprevT, float* __restrict__ hcurT,
    float* __restrict__ hmaxT, int step)
{
    int tid = threadIdx.x;
    int b = tid & 63;
    int bid = blockIdx.x;
    if (bid < 128) {
        int dir = bid >> 6; int rem = bid & 63;
        int jg = rem >> 2, q = rem & 3;
        const float* giT = dir ? giT2_b : giT2_f;
        float* hT        = dir ? hbT   : hfT;
        const float* bhh = dir ? bhh_b : bhh_f;
        int t  = dir ? (Tsz - 1 - step) : step;
        int tp = dir ? (t + 1) : (t - 1);
#pragma unroll
        for (int u = 0; u < 4; u++) {
            int jl = q * 16 + u * 4 + (tid >> 6);
            int j = jg * 64 + jl;
            float gh[3] = {0.f, 0.f, 0.f};
            if (step > 0) {
#pragma unroll
                for (int ks = 0; ks < 8; ks++) {
                    const float* pb = pcap + ((((size_t)dir * 8 + ks) * 16 + jg) * 192) * 64;
#pragma unroll
                    for (int g = 0; g < 3; g++)
                        gh[g] += pb[(size_t)(g * 64 + jl) * 64 + b];
                }
            }
            size_t gc = (size_t)t * 64 + b;
            float gr = giT[(size_t)j * NC + gc];
            float gz = giT[(size_t)(Lsz + j) * NC + gc];
            float gn = giT[(size_t)(2 * Lsz + j) * NC + gc];
            float hp = (step > 0) ? hT[((size_t)tp * Lsz + j) * Bsz + b] : 0.f;
            float r = sigf(gr + gh[0] + bhh[j]);
            float z = sigf(gz + gh[1] + bhh[Lsz + j]);
            float n = tanhf(gn + r * (gh[2] + bhh[2 * Lsz + j]));
            hT[((size_t)t * Lsz + j) * Bsz + b] = (1.f - z) * n + z * hp;
        }
    } else {
        int g2 = bid - 128;
        int i = g2 >> 3; int rest = g2 & 7;
        int jg = rest >> 2, q = rest & 3;
        const float* bih = bihAll + (size_t)i * R3sz;
        const float* bhh = bhhAll + (size_t)i * R3sz;
        const float* p0 = pgen + ((((size_t)i * 2 + 0) * 2 + jg) * 192) * 64;
        const float* p1 = pgen + ((((size_t)i * 2 + 1) * 2 + jg) * 192) * 64;
#pragma unroll
        for (int u = 0; u < 4; u++) {
            int jl = q * 16 + u * 4 + (tid >> 6);
            int j = jg * 64 + jl;
            float sih[3], shh[3];
#pragma unroll
            for (int g = 0; g < 3; g++) {
                sih[g] = p0[(size_t)(g * 64 + jl) * 64 + b];
                shh[g] = (step > 0) ? p1[(size_t)(g * 64 + jl) * 64 + b] : 0.f;
            }
            float r = sigf(sih[0] + bih[j] + shh[0] + bhh[j]);
            float z = sigf(sih[1] + bih[Rsz + j] + shh[1] + bhh[Rsz + j]);
            float n = tanhf(sih[2] + bih[2 * Rsz + j] + r * (shh[2] + bhh[2 * Rsz + j]));
            float hp = (step > 0) ? hprevT[((size_t)i * Rsz + j) * Bsz + b] : 0.f;
            float h = (1.f - z) * n + z * hp;
            size_t idx = ((size_t)i * Rsz + j) * Bsz + b;
            hcurT[idx] = h;
            hmaxT[idx] = (step == 0) ? h : fmaxf(hmaxT[idx], h);
        }
    }
}

// =====================================================================
// txt = (hf+hb)/2 -> row-major txt [b][t][c] AND column txtT [c][t*64+b].
// grid (32, 16).
// =====================================================================
__global__ __launch_bounds__(256) void txt_combine(
    const float* __restrict__ hfT, const float* __restrict__ hbT,
    float* __restrict__ txt, float* __restrict__ txtT)
{
    __shared__ float s[64][65];
    int t = blockIdx.x;
    int c0 = blockIdx.y * 64;
    int tid = threadIdx.x;
#pragma unroll
    for (int l = 0; l < 16; l++) {
        int e = l * 256 + tid;
        int cc = e >> 6, b = e & 63;
        size_t idx = ((size_t)t * Lsz + c0 + cc) * Bsz + b;
        s[cc][b] = 0.5f * (hfT[idx] + hbT[idx]);
    }
    __syncthreads();
#pragma unroll
    for (int l = 0; l < 16; l++) {
        int e = l * 256 + tid;
        int b = e >> 6, cc = e & 63;
        txt[((size_t)b * Tsz + t) * Lsz + c0 + cc] = s[cc][b];
    }
#pragma unroll
    for (int l = 0; l < 16; l++) {
        int e = l * 256 + tid;
        int cc = e >> 6, b = e & 63;
        txtT[(size_t)(c0 + cc) * NC + t * 64 + b] = s[cc][b];
    }
}

// =====================================================================
// Self-attention. v comes as 2 K-split partials vP[z][c][t*64+b];
// summed + bias while staging. grid (64, 8).
// =====================================================================
__global__ __launch_bounds__(256) void attn_kernel(
    const float* __restrict__ q, const float* __restrict__ kmat,
    const float* __restrict__ vP, const float* __restrict__ sa_bv,
    const float* __restrict__ txt,
    const float* __restrict__ gamma_p, float* __restrict__ xattn)
{
    __shared__ float qs[32][129];
    __shared__ float ks[32][129];
    __shared__ float Sc[32][33];
    __shared__ float vs[128][33];
    int b = blockIdx.x;
    int c0 = blockIdx.y * 128;
    int tid = threadIdx.x;
    for (int e = tid; e < Tsz * Rsz; e += 256) {
        qs[e >> 7][e & 127] = q[(size_t)b * Tsz * Rsz + e];
        ks[e >> 7][e & 127] = kmat[(size_t)b * Tsz * Rsz + e];
    }
    for (int e = tid; e < 128 * 32; e += 256) {
        int cc = e >> 5, ss = e & 31;
        size_t base = (size_t)(c0 + cc) * NC + ss * 64 + b;
        float v = sa_bv[c0 + cc];
#pragma unroll
        for (int z = 0; z < 2; z++)
            v += vP[(size_t)z * Lsz * NC + base];
        vs[cc][ss] = v;
    }
    __syncthreads();
    for (int e = tid; e < Tsz * Tsz; e += 256) {
        int t = e >> 5, ss = e & 31;
        float acc = 0.f;
#pragma unroll 4
        for (int o = 0; o < Rsz; o++) acc = fmaf(qs[t][o], ks[ss][o], acc);
        Sc[t][ss] = acc;
    }
    __syncthreads();
    if (tid < 32) {
        int t = tid;
        float mx = -1e30f;
#pragma unroll
        for (int ss = 0; ss < 32; ss++) mx = fmaxf(mx, Sc[t][ss]);
        float sum = 0.f;
        float ex[32];
#pragma unroll
        for (int ss = 0; ss < 32; ss++) { ex[ss] = __expf(Sc[t][ss] - mx); sum += ex[ss]; }
        float inv = 1.f / sum;
#pragma unroll
        for (int ss = 0; ss < 32; ss++) Sc[t][ss] = ex[ss] * inv;
    }
    __syncthreads();
    float gamma = *gamma_p;
    for (int e = tid; e < Tsz * 128; e += 256) {
        int tt = e >> 7, cc = e & 127;
        float acc = 0.f;
#pragma unroll 8
        for (int ss = 0; ss < Tsz; ss++)
            acc = fmaf(Sc[tt][ss], vs[cc][ss], acc);
        size_t oidx = ((size_t)b * Tsz + tt) * Lsz + c0 + cc;
        xattn[oidx] = gamma * acc + txt[oidx];
    }
}

// ---------------- length-masked mean pool, grid (64,4) ----------------
__global__ __launch_bounds__(256) void pool_kernel(
    const float* __restrict__ xattn, const int* __restrict__ lens,
    float* __restrict__ txt_embed)
{
    int b = blockIdx.x;
    int c = blockIdx.y * 256 + threadIdx.x;
    int len = lens[b];
    float s = 0.f;
    for (int t = 0; t < len; t++) s += xattn[((size_t)b * Tsz + t) * Lsz + c];
    txt_embed[(size_t)b * Lsz + c] = s / (float)len;
}

// =====================================================================
// base_fcT[n][b] = dot(txt_emb[b][:], W_txt_fc[n][0:1024]). grid 256.
// =====================================================================
__global__ __launch_bounds__(256) void basefc_kernel(
    const float* __restrict__ temb, const float* __restrict__ W,
    float* __restrict__ outT)
{
    int lane = threadIdx.x & 63, w = threadIdx.x >> 6;
    int n = blockIdx.x * 4 + w;
    const float* wr = W + (size_t)n * (Rsz + Lsz) + lane * 16;
    float wv[16];
#pragma unroll
    for (int u = 0; u < 4; u++) *(float4*)&wv[u * 4] = *(const float4*)&wr[u * 4];
    for (int b = 0; b < Bsz; b++) {
        const float* te = temb + (size_t)b * Lsz + lane * 16;
        float tv[16];
#pragma unroll
        for (int u = 0; u < 4; u++) *(float4*)&tv[u * 4] = *(const float4*)&te[u * 4];
        float a = 0.f;
#pragma unroll
        for (int u = 0; u < 16; u++) a = fmaf(wv[u], tv[u], a);
#pragma unroll
        for (int off = 32; off; off >>= 1) a += __shfl_down(a, off, 64);
        if (lane == 0) outT[(size_t)n * Bsz + b] = a;
    }
}

// ---- hmaxT [i][j][b] -> hstdT [j][i*64+b], coalesced permute. grid 64 ----
__global__ __launch_bounds__(256) void hstdT_kernel(
    const float* __restrict__ hmaxT, float* __restrict__ hstdT)
{
    int i = blockIdx.x, tid = threadIdx.x;
    int b = tid & 63, j0 = tid >> 6;
#pragma unroll
    for (int l = 0; l < 32; l++) {
        int j = l * 4 + j0;
        hstdT[(size_t)j * 4096 + i * 64 + b] = hmaxT[((size_t)i * Rsz + j) * Bsz + b];
    }
}

// =====================================================================
// sims partial reduce: column layouts, fully coalesced. grid (64, 4).
// =====================================================================
__global__ __launch_bounds__(256) void sims_part(
    const float* __restrict__ fcT, const float* __restrict__ base_fcT,
    const float* __restrict__ bfc, const float* __restrict__ iv,
    float* __restrict__ accA, float* __restrict__ accB)
{
    int i = blockIdx.x, cs = blockIdx.y;
    int tid = threadIdx.x;
    int w = tid >> 6, b = tid & 63;
    float s1 = 0.f, s2 = 0.f;
    for (int u = 0; u < 64; u++) {
        int c = cs * 256 + w * 64 + u;
        float f = fcT[(size_t)c * 4096 + i * 64 + b] + base_fcT[(size_t)c * Bsz + b] + bfc[c];
        s1 = fmaf(f, f, s1);
        s2 = fmaf(f, iv[(size_t)i * Lsz + c], s2);
    }
    int m = i * 64 + b;
    atomicAdd(&accA[m], s1);
    atomicAdd(&accB[m], s2);
}

__global__ __launch_bounds__(256) void sims_final(
    const float* __restrict__ accA, const float* __restrict__ accB,
    float* __restrict__ out)
{
    int m = blockIdx.x * 256 + threadIdx.x;
    out[m] = accB[m] / (sqrtf(accA[m]) + 1e-8f);
}

// =====================================================================
extern "C" void kernel_launch(void* const* d_in, const int* in_sizes, int n_in,
                              void* d_out, int out_size, void* d_ws, size_t ws_size,
                              hipStream_t stream)
{
    const float* img_embed    = (const float*)d_in[0];
    const float* cap_embed    = (const float*)d_in[1];
    const int*   lens         = (const int*)d_in[2];
    const float* W_reduce_img = (const float*)d_in[3];
    const float* b_reduce_img = (const float*)d_in[4];
    const float* W_reduce_txt = (const float*)d_in[5];
    const float* b_reduce_txt = (const float*)d_in[6];
    const float* gru_Wih_f    = (const float*)d_in[7];
    const float* gru_Whh_f    = (const float*)d_in[8];
    const float* gru_bih_f    = (const float*)d_in[9];
    const float* gru_bhh_f    = (const float*)d_in[10];
    const float* gru_Wih_b    = (const float*)d_in[11];
    const float* gru_Whh_b    = (const float*)d_in[12];
    const float* gru_bih_b    = (const float*)d_in[13];
    const float* gru_bhh_b    = (const float*)d_in[14];
    const float* sa_Wq        = (const float*)d_in[15];
    const float* sa_bq        = (const float*)d_in[16];
    const float* sa_Wk        = (const float*)d_in[17];
    const float* sa_bk        = (const float*)d_in[18];
    const float* sa_Wv        = (const float*)d_in[19];
    const float* sa_bv        = (const float*)d_in[20];
    const float* sa_gamma     = (const float*)d_in[21];
    const float* gen_Wih      = (const float*)d_in[22];
    const float* gen_bih      = (const float*)d_in[23];
    const float* gen_Whh      = (const float*)d_in[24];
    const float* gen_bhh      = (const float*)d_in[25];
    const float* gen_Wbih     = (const float*)d_in[26];
    const float* gen_bbih     = (const float*)d_in[27];
    const float* gen_Wbhh     = (const float*)d_in[28];
    const float* gen_bbhh     = (const float*)d_in[29];
    const float* W_txt_fc     = (const float*)d_in[30];
    const float* b_txt_fc     = (const float*)d_in[31];

    float* ws = (float*)d_ws;
    size_t off = 0;
    auto alloc = [&](size_t n) { float* p = ws + off; off += n; return p; };
    float* giT2_f   = alloc((size_t)H3sz * NC);
    float* giT2_b   = alloc((size_t)H3sz * NC);
    float* hfT      = alloc((size_t)Tsz * Lsz * Bsz);
    float* hbT      = alloc((size_t)Tsz * Lsz * Bsz);
    float* capTr    = alloc((size_t)KPAD * NC);
    float* capT2    = alloc((size_t)Rsz * NC);
    float* txt      = alloc((size_t)Bsz * Tsz * Lsz);
    float* txtT     = alloc((size_t)Lsz * NC);
    float* qbuf     = alloc((size_t)Bsz * Tsz * Rsz);
    float* kbuf     = alloc((size_t)Bsz * Tsz * Rsz);
    float* qP       = alloc((size_t)8 * Rsz * NC);
    float* kP       = alloc((size_t)8 * Rsz * NC);
    float* vP       = alloc((size_t)2 * Lsz * NC);
    float* xattn    = alloc((size_t)Bsz * Tsz * Lsz);
    float* txt_emb  = alloc((size_t)Bsz * Lsz);
    float* base     = alloc((size_t)Bsz * Rsz);
    float* iv       = alloc((size_t)Bsz * Lsz);
    float* WihAllT  = alloc((size_t)Bsz * GENROWS);
    float* WhhAllT  = alloc((size_t)Bsz * GENROWS);
    float* WhhT_f   = alloc((size_t)Lsz * H3sz);
    float* WhhT_b   = alloc((size_t)Lsz * H3sz);
    float* WihT_f   = alloc((size_t)KPAD * H3sz);
    float* WihT_b   = alloc((size_t)KPAD * H3sz);
    float* WrtT     = alloc((size_t)KPAD * Rsz);
    float* WvT      = alloc((size_t)Lsz * Lsz);
    float* WqT      = alloc((size_t)Lsz * Rsz);
    float* WkT      = alloc((size_t)Lsz * Rsz);
    float* WfcT     = alloc((size_t)Rsz * Lsz);
    float* bihAll   = alloc((size_t)Bsz * R3sz);
    float* bhhAll   = alloc((size_t)Bsz * R3sz);
    float* hA       = alloc((size_t)Bsz * Rsz * Bsz);
    float* hB       = alloc((size_t)Bsz * Rsz * Bsz);
    float* hmaxT    = alloc((size_t)Bsz * Rsz * Bsz);
    float* hstdT    = alloc((size_t)Rsz * Bsz * Bsz);
    float* base_fcT = alloc((size_t)Lsz * Bsz);
    float* fcT      = alloc((size_t)Lsz * Bsz * Bsz);
    float* accA     = alloc(4096);
    float* accB     = alloc(4096);
    // Aliases (disjoint lifetimes):
    float* pcap = fcT;        // 3.15M floats in fcT (4.19M); fcT written later
    float* pgen = vP;         // 3.15M floats in vP (4.19M); vP written later

    // 0) zero the sims accumulators
    hipMemsetAsync(accA, 0, 2 * 4096 * sizeof(float), stream);

    // 1) one-time transposes
    transp_kernel<<<dim3(16, 48), 256, 0, stream>>>(gru_Whh_f, WhhT_f, H3sz, Lsz, Lsz, Lsz, 0);
    transp_kernel<<<dim3(16, 48), 256, 0, stream>>>(gru_Whh_b, WhhT_b, H3sz, Lsz, Lsz, Lsz, 0);
    transp_kernel<<<dim3(5, 48), 256, 0, stream>>>(gru_Wih_f, WihT_f, H3sz, DIN, KPAD, DIN, 0);
    transp_kernel<<<dim3(5, 48), 256, 0, stream>>>(gru_Wih_b, WihT_b, H3sz, DIN, KPAD, DIN, 0);
    transp_kernel<<<dim3(5, 2), 256, 0, stream>>>(W_reduce_txt, WrtT, Rsz, DIN, KPAD, DIN, 0);
    transp_kernel<<<dim3(16, 16), 256, 0, stream>>>(sa_Wv, WvT, Lsz, Lsz, Lsz, Lsz, 0);
    transp_kernel<<<dim3(16, 2), 256, 0, stream>>>(sa_Wq, WqT, Rsz, Lsz, Lsz, Lsz, 0);
    transp_kernel<<<dim3(16, 2), 256, 0, stream>>>(sa_Wk, WkT, Rsz, Lsz, Lsz, Lsz, 0);
    transp_kernel<<<dim3(2, 16), 256, 0, stream>>>(W_txt_fc, WfcT, Lsz, Rsz, Rsz, Rsz + Lsz, Lsz);
    captr_kernel<<<dim3(32, 5), 256, 0, stream>>>(cap_embed, capTr);

    // 2) image-side precompute + generated weights (directly transposed)
    img_kernel<<<64, 256, 0, stream>>>(img_embed, W_reduce_img, b_reduce_img, base, iv);
    genw_gemm<<<dim3(3, 129, 2), 256, 0, stream>>>(gen_Wih, gen_bih, gen_Whh, gen_bhh,
        gen_Wbih, gen_bbih, gen_Wbhh, gen_bbhh, base, WihAllT, WhhAllT, bihAll, bhhAll);

    // 3) gi (both dirs) + cap_reduced
    gemm_tt<<<dim3(16, 24, 2), 256, 0, stream>>>(WihT_f, WihT_b, capTr,
        gru_bih_f, gru_bih_b, giT2_f, giT2_b, H3sz);
    gemm_tt<<<dim3(16, 1, 1), 256, 0, stream>>>(WrtT, WrtT, capTr,
        b_reduce_txt, b_reduce_txt, capT2, capT2, Rsz);

    // 4) recurrences
    for (int s = 0; s < Tsz; s++) {
        const float* hp = (s & 1) ? hA : hB;   // unused at s==0
        float* hc = (s & 1) ? hB : hA;
        if (s == 0) hp = hA;
        step_gemm2<<<512, 256, 0, stream>>>(hfT, hbT, WhhT_f, WhhT_b,
            capT2, WihAllT, WhhAllT, hp, pcap, pgen, s);
        step_gates2<<<640, 256, 0, stream>>>(pcap, pgen, giT2_f, giT2_b, hfT, hbT,
            gru_bhh_f, gru_bhh_b, bihAll, bhhAll, hp, hc, hmaxT, s);
    }
    hstdT_kernel<<<64, 256, 0, stream>>>(hmaxT, hstdT);

    // 5) combine + self-attention (q/k/v all via K-split TT GEMMs)
    txt_combine<<<dim3(32, 16), 256, 0, stream>>>(hfT, hbT, txt, txtT);
    gemm_qk<<<dim3(16, 2, 8), 256, 0, stream>>>(WqT, WkT, txtT, qP, kP);
    gemm_ttp<<<dim3(16, 8, 2), 256, 0, stream>>>(WvT, txtT, vP, Lsz, NC, 512);
    qkc_kernel<<<dim3(32, 2), 256, 0, stream>>>(qP, kP, sa_bq, sa_bk, qbuf, kbuf);
    attn_kernel<<<dim3(64, 8), 256, 0, stream>>>(qbuf, kbuf, vP, sa_bv, txt,
        sa_gamma, xattn);

    // 6) pool + image-independent FC part (transposed output)
    pool_kernel<<<dim3(64, 4), 256, 0, stream>>>(xattn, lens, txt_emb);
    basefc_kernel<<<256, 256, 0, stream>>>(txt_emb, W_txt_fc, base_fcT);

    // 7) fc delta (column layout) + sims partial/final
    gemm_ttp<<<dim3(32, 8, 1), 256, 0, stream>>>(WfcT, hstdT, fcT, Lsz, 4096, Rsz);
    sims_part<<<dim3(64, 4), 256, 0, stream>>>(fcT, base_fcT, b_txt_fc, iv, accA, accB);
    sims_final<<<16, 256, 0, stream>>>(accA, accB, (float*)d_out);
}